// Round 4
// baseline (1449.957 us; speedup 1.0000x reference)
//
#include <hip/hip_runtime.h>
#include <hip/hip_bf16.h>
#include <stdint.h>

using bf16 = __hip_bfloat16;

#define NN 50000
#define NE 400000
#define NG 64
#define NHEADS 4
#define FIN 64
#define HID 96
#define CC3 64
#define NOUT 10

__device__ __forceinline__ float b2f(bf16 h){ return __bfloat162float(h); }
__device__ __forceinline__ bf16 f2b(float f){ return __float2bfloat16(f); }
__device__ __forceinline__ bool is_ok(float v){ return (v==v) && (fabsf(v) <= 1e30f); }
__device__ __forceinline__ float scrub(float v){ return is_ok(v) ? v : 0.f; }

__device__ __forceinline__ float wave_max_f(float v){
  #pragma unroll
  for (int m=1;m<64;m<<=1) v = fmaxf(v, __shfl_xor(v,m));
  return v;
}
__device__ __forceinline__ float wave_sum_f(float v){
  #pragma unroll
  for (int m=1;m<64;m<<=1) v += __shfl_xor(v,m);
  return v;
}

// ---------------- prologue: cast f32 inputs -> bf16 workspace copies ----------------
#define NJOBS 16
struct CastJobs {
  const float* src[NJOBS];
  bf16*        dst[NJOBS];
  int          n[NJOBS];
};
__global__ __launch_bounds__(256) void cast_kernel(CastJobs j){
  for (int t=0; t<NJOBS; ++t){
    int n = j.n[t];
    const float* s = j.src[t];
    bf16* d = j.dst[t];
    for (int i = blockIdx.x*256 + threadIdx.x; i < n; i += gridDim.x*256)
      d[i] = f2b(s[i]);
  }
}

// ---------------- CSR build ----------------
__global__ void deg_kernel(const int* __restrict__ ei, int* __restrict__ deg){
  int e = blockIdx.x*256 + threadIdx.x;
  if (e < NE){
    unsigned d = (unsigned)ei[NE + e];
    if (d >= NN) d = 0;                       // defensive
    atomicAdd(&deg[d], 1);
  }
}

// single-wave exclusive scan
__global__ __launch_bounds__(64) void scan64_kernel(const int* __restrict__ deg,
                                                    int* __restrict__ off,
                                                    int* __restrict__ cursor){
  int lane = threadIdx.x;
  int carry = 0;
  for (int base=0; base<NN; base+=64){
    int i = base + lane;
    int v = (i<NN) ? deg[i] : 0;
    int x = v;
    #pragma unroll
    for (int s=1;s<64;s<<=1){ int t = __shfl_up(x, s); if (lane >= s) x += t; }
    int ex = carry + x - v;                  // exclusive prefix
    if (i<NN){ off[i]=ex; cursor[i]=ex; }
    carry += __shfl(x, 63);
  }
  if (lane==0) off[NN] = carry;
}

__global__ void scatter_kernel(const int* __restrict__ ei, int* __restrict__ cursor,
                               int* __restrict__ csr_src){
  int e = blockIdx.x*256 + threadIdx.x;
  if (e < NE){
    unsigned d = (unsigned)ei[NE + e];
    if (d >= NN) d = 0;                       // defensive
    int slot = atomicAdd(&cursor[d], 1);
    if (slot < 0) slot = 0;
    if (slot >= NE) slot = NE-1;              // defensive
    unsigned s = (unsigned)ei[e];
    if (s >= NN) s = 0;                       // defensive
    csr_src[slot] = (int)s;
  }
}

// ---------------- GEMM: out(bf16) = A(bf16,[M,K]) @ B(bf16,[K,Nc]) + bias ----------------
template<int K>
__global__ __launch_bounds__(256) void gemm_bias(const bf16* __restrict__ A,
    const bf16* __restrict__ B, const bf16* __restrict__ bias,
    bf16* __restrict__ outp, int Mrows, int Nc)
{
  __shared__ float Ast[K][65];   // transposed: Ast[k][row]
  __shared__ float Bs[K][64];
  const int tid = threadIdx.x;
  const int r0 = blockIdx.x*64, c0 = blockIdx.y*64;

  for (int idx = tid; idx < 64*K/2; idx += 256){
    int flat = idx*2; int r = flat / K; int k = flat % K;
    int row = r0 + r;
    unsigned int u = 0;
    if (row < Mrows) u = *(const unsigned int*)(A + (size_t)row*K + k);
    Ast[k][r]   = __uint_as_float(u << 16);
    Ast[k+1][r] = __uint_as_float(u & 0xffff0000u);
  }
  for (int idx = tid; idx < K*64/2; idx += 256){
    int flat = idx*2; int k = flat / 64; int c = flat % 64;
    int col = c0 + c;
    unsigned int u = 0;
    if (col + 1 < Nc) u = *(const unsigned int*)(B + (size_t)k*Nc + col);
    Bs[k][c]   = __uint_as_float(u << 16);
    Bs[k][c+1] = __uint_as_float(u & 0xffff0000u);
  }
  __syncthreads();

  int tx = tid & 15, ty = tid >> 4;
  float acc[4][4] = {};
  #pragma unroll 4
  for (int k=0;k<K;++k){
    float a[4], b[4];
    #pragma unroll
    for (int i=0;i<4;++i) a[i] = Ast[k][ty*4+i];
    #pragma unroll
    for (int j=0;j<4;++j) b[j] = Bs[k][tx*4+j];
    #pragma unroll
    for (int i=0;i<4;++i)
      #pragma unroll
      for (int j=0;j<4;++j)
        acc[i][j] += a[i]*b[j];
  }
  #pragma unroll
  for (int i=0;i<4;++i){
    int row = r0 + ty*4 + i;
    if (row >= Mrows) continue;
    #pragma unroll
    for (int j=0;j<4;++j){
      int col = c0 + tx*4 + j;
      if (col >= Nc) continue;
      outp[(size_t)row*Nc + col] = f2b(scrub(acc[i][j] + b2f(bias[col])));
    }
  }
}

// ---------------- per-node attention logits ----------------
__global__ void logits_kernel(const bf16* __restrict__ M, const bf16* __restrict__ att,
                              float* __restrict__ L, int C){
  int t = blockIdx.x*256 + threadIdx.x;
  if (t >= NN*NHEADS) return;
  int n = t >> 2, h = t & 3;
  const bf16* row = M + (size_t)n*NHEADS*C + h*C;
  const bf16* av  = att + h*C;
  float acc = 0.f;
  for (int c=0;c<C;++c) acc += b2f(row[c]) * b2f(av[c]);
  acc = scrub(acc);
  L[t] = (acc >= 0.f) ? acc : 0.2f*acc;
}

// ---------------- conv aggregation: one wave per dst node ----------------
template<int C>
__global__ __launch_bounds__(256) void conv_agg(const int* __restrict__ off,
    const int* __restrict__ csr_src, const float* __restrict__ L,
    const bf16* __restrict__ Mmsg, const bf16* __restrict__ Hself,
    bf16* __restrict__ Hout)
{
  constexpr int R = 4*C;
  __shared__ float red[4][R];
  const int wave = threadIdx.x >> 6, lane = threadIdx.x & 63;
  const int n = blockIdx.x*4 + wave;
  int e0 = off[n], e1 = off[n+1];
  if (e0 < 0) e0 = 0;  if (e0 > NE) e0 = NE;      // defensive
  if (e1 < e0) e1 = e0; if (e1 > NE) e1 = NE;

  // phase A: segment max of logits
  float4 m4 = make_float4(-INFINITY,-INFINITY,-INFINITY,-INFINITY);
  for (int i=e0+lane; i<e1; i+=64){
    unsigned s = (unsigned)csr_src[i]; if (s >= NN) s = 0;
    float4 l4 = *(const float4*)(L + 4*(size_t)s);
    m4.x=fmaxf(m4.x,l4.x); m4.y=fmaxf(m4.y,l4.y); m4.z=fmaxf(m4.z,l4.z); m4.w=fmaxf(m4.w,l4.w);
  }
  m4.x=wave_max_f(m4.x); m4.y=wave_max_f(m4.y); m4.z=wave_max_f(m4.z); m4.w=wave_max_f(m4.w);

  // phase B: denom
  float4 dn = make_float4(0,0,0,0);
  for (int i=e0+lane; i<e1; i+=64){
    unsigned s = (unsigned)csr_src[i]; if (s >= NN) s = 0;
    float4 l4 = *(const float4*)(L + 4*(size_t)s);
    dn.x += __expf(l4.x-m4.x); dn.y += __expf(l4.y-m4.y);
    dn.z += __expf(l4.z-m4.z); dn.w += __expf(l4.w-m4.w);
  }
  dn.x=wave_sum_f(dn.x); dn.y=wave_sum_f(dn.y); dn.z=wave_sum_f(dn.z); dn.w=wave_sum_f(dn.w);
  float4 rden = make_float4(1.f/(dn.x+1e-16f), 1.f/(dn.y+1e-16f),
                            1.f/(dn.z+1e-16f), 1.f/(dn.w+1e-16f));

  // phase C: weighted gather-accumulate. lane handles 8 bf16 channels.
  const bool active = (8*lane) < R;
  const int hidx = (8*lane) / C;
  float acc[8] = {0,0,0,0,0,0,0,0};
  for (int e=e0; e<e1; ++e){
    unsigned s = (unsigned)csr_src[e]; if (s >= NN) s = 0;
    float4 l4 = *(const float4*)(L + 4*(size_t)s);
    float w0 = __expf(l4.x-m4.x)*rden.x;
    float w1 = __expf(l4.y-m4.y)*rden.y;
    float w2 = __expf(l4.z-m4.z)*rden.z;
    float w3 = __expf(l4.w-m4.w)*rden.w;
    float wl = (hidx==0)?w0:(hidx==1)?w1:(hidx==2)?w2:w3;
    if (active){
      const uint4* q = (const uint4*)(Mmsg + (size_t)s*R) + lane;
      uint4 u = *q;
      acc[0] += __uint_as_float(u.x<<16)*wl;  acc[1] += __uint_as_float(u.x&0xffff0000u)*wl;
      acc[2] += __uint_as_float(u.y<<16)*wl;  acc[3] += __uint_as_float(u.y&0xffff0000u)*wl;
      acc[4] += __uint_as_float(u.z<<16)*wl;  acc[5] += __uint_as_float(u.z&0xffff0000u)*wl;
      acc[6] += __uint_as_float(u.w<<16)*wl;  acc[7] += __uint_as_float(u.w&0xffff0000u)*wl;
    }
  }
  if (active){
    #pragma unroll
    for (int j=0;j<8;++j) red[wave][8*lane+j] = acc[j];
  }
  __syncthreads();

  // epilogue: mean over heads + self (in-place safe: one thread per element)
  for (int c=lane; c<C; c+=64){
    float v = 0.25f*(red[wave][c] + red[wave][C+c] + red[wave][2*C+c] + red[wave][3*C+c]);
    float sv = b2f(Hself[(size_t)n*C + c]);
    Hout[(size_t)n*C + c] = f2b(scrub(v + sv));
  }
}

// ---------------- global mean pool ----------------
__global__ __launch_bounds__(256) void pool_kernel(const bf16* __restrict__ H3,
    const int* __restrict__ batch, float* __restrict__ pooled){
  int g = blockIdx.x;
  __shared__ int sb[2];
  if (threadIdx.x < 2){
    int target = g + threadIdx.x;
    int lo=0, hi=NN;
    while (lo<hi){ int mid=(lo+hi)>>1; if (batch[mid]<target) lo=mid+1; else hi=mid; }
    sb[threadIdx.x]=lo;
  }
  __syncthreads();
  int start=sb[0], end=sb[1];
  int c = threadIdx.x & 63, rg = threadIdx.x >> 6;
  float acc=0.f;
  for (int r=start+rg; r<end; r+=4) acc += b2f(H3[(size_t)r*CC3 + c]);
  __shared__ float red[256];
  red[threadIdx.x]=acc; __syncthreads();
  if (threadIdx.x < 64){
    float s = red[c]+red[64+c]+red[128+c]+red[192+c];
    float cnt = (float)(end-start);
    pooled[g*CC3 + c] = scrub(s / fmaxf(cnt, 1.0f));
  }
}

// ---------------- classifier + log_softmax (f32 output) ----------------
__global__ __launch_bounds__(64) void fc_kernel(const float* __restrict__ pooled,
    const bf16* __restrict__ Wfc, const bf16* __restrict__ bfc, float* __restrict__ out){
  int g = blockIdx.x, t = threadIdx.x;
  __shared__ float p[CC3];
  __shared__ float lg[NOUT];
  p[t] = scrub(pooled[g*CC3 + t]);
  __syncthreads();
  if (t < NOUT){
    float a = b2f(bfc[t]);
    for (int c=0;c<CC3;++c) a += p[c]*b2f(Wfc[c*NOUT + t]);
    lg[t] = scrub(a);
  }
  __syncthreads();
  if (t < NOUT){
    float m = -INFINITY;
    #pragma unroll
    for (int i=0;i<NOUT;++i) m = fmaxf(m, lg[i]);
    float s = 0.f;
    #pragma unroll
    for (int i=0;i<NOUT;++i) s += __expf(lg[i]-m);
    out[g*NOUT + t] = scrub(lg[t] - m - __logf(s));
  }
}

extern "C" void kernel_launch(void* const* d_in, const int* in_sizes, int n_in,
                              void* d_out, int out_size, void* d_ws, size_t ws_size,
                              hipStream_t stream) {
  // ---- inputs are FLOAT32 per the reference (jnp.float32 everywhere) ----
  const float* xf    = (const float*)d_in[0];
  const int*   ei    = (const int*)d_in[1];
  const int*   batch = (const int*)d_in[2];
  const float* pWm1  = (const float*)d_in[3];
  const float* pbm1  = (const float*)d_in[4];
  const float* patt1 = (const float*)d_in[5];
  const float* pWs1  = (const float*)d_in[6];
  const float* pbs1  = (const float*)d_in[7];
  const float* pWm2  = (const float*)d_in[8];
  const float* pbm2  = (const float*)d_in[9];
  const float* patt2 = (const float*)d_in[10];
  const float* pWm3  = (const float*)d_in[11];
  const float* pbm3  = (const float*)d_in[12];
  const float* patt3 = (const float*)d_in[13];
  const float* pWs3  = (const float*)d_in[14];
  const float* pbs3  = (const float*)d_in[15];
  const float* pWfc  = (const float*)d_in[16];
  const float* pbfc  = (const float*)d_in[17];

  // ---- workspace layout (~68 MB), lifetime-aliased ----
  char* p = (char*)d_ws;
  auto alloc = [&](size_t bytes)->char*{ char* q = p; p += (bytes + 255) & ~(size_t)255; return q; };
  int*   deg     = (int*)  alloc(NN*sizeof(int));
  int*   off     = (int*)  alloc((NN+1)*sizeof(int));
  int*   cursor  = (int*)  alloc(NN*sizeof(int));
  int*   csr_src = (int*)  alloc(NE*sizeof(int));
  float* L       = (float*)alloc((size_t)NN*4*sizeof(float));
  bf16*  Mb      = (bf16*) alloc((size_t)NN*384*sizeof(bf16));   // 38.4 MB, reused per layer
  bf16*  H1b     = (bf16*) alloc((size_t)NN*96*sizeof(bf16));    // 9.6 MB; H3 aliases this
  bf16*  H2b     = (bf16*) alloc((size_t)NN*96*sizeof(bf16));    // 9.6 MB
  float* pooled  = (float*)alloc((size_t)NG*CC3*sizeof(float));
  bf16*  xb      = (bf16*) alloc((size_t)NN*FIN*sizeof(bf16));   // 6.4 MB
  bf16*  Wm1 = (bf16*)alloc(FIN*384*sizeof(bf16));
  bf16*  bm1 = (bf16*)alloc(384*sizeof(bf16));
  bf16*  att1= (bf16*)alloc(384*sizeof(bf16));
  bf16*  Ws1 = (bf16*)alloc(FIN*96*sizeof(bf16));
  bf16*  bs1 = (bf16*)alloc(96*sizeof(bf16));
  bf16*  Wm2 = (bf16*)alloc(HID*384*sizeof(bf16));
  bf16*  bm2 = (bf16*)alloc(384*sizeof(bf16));
  bf16*  att2= (bf16*)alloc(384*sizeof(bf16));
  bf16*  Wm3 = (bf16*)alloc(HID*256*sizeof(bf16));
  bf16*  bm3 = (bf16*)alloc(256*sizeof(bf16));
  bf16*  att3= (bf16*)alloc(256*sizeof(bf16));
  bf16*  Ws3 = (bf16*)alloc(HID*64*sizeof(bf16));
  bf16*  bs3 = (bf16*)alloc(64*sizeof(bf16));
  bf16*  Wfc = (bf16*)alloc(CC3*NOUT*sizeof(bf16));
  bf16*  bfc = (bf16*)alloc(NOUT*sizeof(bf16));
  bf16*  H3b = H1b;   // H1 dead after layer-2 aggregation (stream-ordered)

  // ---- prologue: cast f32 -> bf16 ----
  CastJobs cj;
  int ji = 0;
  auto addj = [&](const float* s, bf16* d, int n){ cj.src[ji]=s; cj.dst[ji]=d; cj.n[ji]=n; ++ji; };
  addj(xf,   xb,   NN*FIN);
  addj(pWm1, Wm1,  FIN*384); addj(pbm1, bm1, 384); addj(patt1, att1, 384);
  addj(pWs1, Ws1,  FIN*96);  addj(pbs1, bs1, 96);
  addj(pWm2, Wm2,  HID*384); addj(pbm2, bm2, 384); addj(patt2, att2, 384);
  addj(pWm3, Wm3,  HID*256); addj(pbm3, bm3, 256); addj(patt3, att3, 256);
  addj(pWs3, Ws3,  HID*64);  addj(pbs3, bs3, 64);
  addj(pWfc, Wfc,  CC3*NOUT); addj(pbfc, bfc, NOUT);
  cast_kernel<<<2048, 256, 0, stream>>>(cj);

  // ---- CSR build (reused by all 3 layers) ----
  hipMemsetAsync(deg, 0, NN*sizeof(int), stream);
  hipMemsetAsync(csr_src, 0, NE*sizeof(int), stream);   // defensive: gaps -> node 0
  deg_kernel<<<(NE+255)/256, 256, 0, stream>>>(ei, deg);
  scan64_kernel<<<1, 64, 0, stream>>>(deg, off, cursor);
  scatter_kernel<<<(NE+255)/256, 256, 0, stream>>>(ei, cursor, csr_src);

  const int RB = (NN + 63)/64;            // 782 row blocks
  const int LB = (NN*4 + 255)/256;        // logits blocks
  const int AB = NN/4;                    // 12500 agg blocks (4 waves each)

  // ---- layer 1: FIN=64 -> HID=96 ----
  gemm_bias<64><<<dim3(RB,2), 256, 0, stream>>>(xb, Ws1, bs1, H1b, NN, 96);  // self pre-fill
  gemm_bias<64><<<dim3(RB,6), 256, 0, stream>>>(xb, Wm1, bm1, Mb, NN, 384);
  logits_kernel<<<LB, 256, 0, stream>>>(Mb, att1, L, 96);
  conv_agg<96><<<AB, 256, 0, stream>>>(off, csr_src, L, Mb, H1b, H1b);       // in-place += agg

  // ---- layer 2: HID -> HID (identity self) ----
  gemm_bias<96><<<dim3(RB,6), 256, 0, stream>>>(H1b, Wm2, bm2, Mb, NN, 384);
  logits_kernel<<<LB, 256, 0, stream>>>(Mb, att2, L, 96);
  conv_agg<96><<<AB, 256, 0, stream>>>(off, csr_src, L, Mb, H1b, H2b);

  // ---- layer 3: HID -> CC3=64 ----
  gemm_bias<96><<<dim3(RB,4), 256, 0, stream>>>(H2b, Wm3, bm3, Mb, NN, 256);
  gemm_bias<96><<<dim3(RB,1), 256, 0, stream>>>(H2b, Ws3, bs3, H3b, NN, 64); // self pre-fill (over H1)
  logits_kernel<<<LB, 256, 0, stream>>>(Mb, att3, L, 64);
  conv_agg<64><<<AB, 256, 0, stream>>>(off, csr_src, L, Mb, H3b, H3b);       // in-place += agg

  // ---- pool + classifier ----
  pool_kernel<<<NG, 256, 0, stream>>>(H3b, batch, pooled);
  fc_kernel<<<NG, 64, 0, stream>>>(pooled, Wfc, bfc, (float*)d_out);
}

// Round 5
// 1082.300 us; speedup vs baseline: 1.3397x; 1.3397x over previous
//
#include <hip/hip_runtime.h>
#include <hip/hip_bf16.h>
#include <stdint.h>

using bf16 = __hip_bfloat16;

#define NN 50000
#define NE 400000
#define NG 64
#define NHEADS 4
#define FIN 64
#define HID 96
#define CC3 64
#define NOUT 10

#define SCAN_BLOCK 256
#define NPART ((NN + SCAN_BLOCK - 1) / SCAN_BLOCK)   // 196 (<=256)

__device__ __forceinline__ float b2f(bf16 h){ return __bfloat162float(h); }
__device__ __forceinline__ bf16 f2b(float f){ return __float2bfloat16(f); }

__device__ __forceinline__ float wave_max_f(float v){
  #pragma unroll
  for (int m=1;m<64;m<<=1) v = fmaxf(v, __shfl_xor(v,m));
  return v;
}
__device__ __forceinline__ float wave_sum_f(float v){
  #pragma unroll
  for (int m=1;m<64;m<<=1) v += __shfl_xor(v,m);
  return v;
}

// ---------------- prologue: cast f32 inputs -> bf16 workspace copies ----------------
#define NJOBS 16
struct CastJobs {
  const float* src[NJOBS];
  bf16*        dst[NJOBS];
  int          n[NJOBS];
};
__global__ __launch_bounds__(256) void cast_kernel(CastJobs j){
  for (int t=0; t<NJOBS; ++t){
    int n = j.n[t];
    const float* s = j.src[t];
    bf16* d = j.dst[t];
    for (int i = blockIdx.x*256 + threadIdx.x; i < n; i += gridDim.x*256)
      d[i] = f2b(s[i]);
  }
}

// ---------------- CSR build ----------------
__global__ void deg_kernel(const int* __restrict__ ei, int* __restrict__ deg){
  int e = blockIdx.x*256 + threadIdx.x;
  if (e < NE) atomicAdd(&deg[ei[NE + e]], 1);
}

// pass 1: per-block sums of deg
__global__ __launch_bounds__(256) void scan_part_kernel(const int* __restrict__ deg,
                                                        int* __restrict__ partials){
  int i = blockIdx.x*SCAN_BLOCK + threadIdx.x;
  int v = (i < NN) ? deg[i] : 0;
  __shared__ int ws[4];
  int lane = threadIdx.x & 63, w = threadIdx.x >> 6;
  int s = v;
  #pragma unroll
  for (int m=1;m<64;m<<=1) s += __shfl_xor(s,m);
  if (lane==0) ws[w]=s;
  __syncthreads();
  if (threadIdx.x==0) partials[blockIdx.x] = ws[0]+ws[1]+ws[2]+ws[3];
}

// pass 2: single-block exclusive scan of the 196 partials (in place) + total -> off[NN]
__global__ __launch_bounds__(256) void scan_top_kernel(int* __restrict__ partials,
                                                       int* __restrict__ off){
  __shared__ int buf[256];
  int t = threadIdx.x;
  int v = (t < NPART) ? partials[t] : 0;
  buf[t] = v; __syncthreads();
  for (int s=1;s<256;s<<=1){
    int x = (t>=s) ? buf[t-s] : 0;
    __syncthreads();
    buf[t] += x;
    __syncthreads();
  }
  if (t < NPART) partials[t] = buf[t] - v;   // exclusive
  if (t == 0) off[NN] = buf[255];            // padded lanes add 0 -> total
}

// pass 3: per-block local exclusive scan + block offset
__global__ __launch_bounds__(256) void scan_final_kernel(const int* __restrict__ deg,
    const int* __restrict__ partials, int* __restrict__ off, int* __restrict__ cursor){
  __shared__ int buf[256];
  int i = blockIdx.x*SCAN_BLOCK + threadIdx.x;
  int t = threadIdx.x;
  int v = (i<NN) ? deg[i] : 0;
  buf[t] = v; __syncthreads();
  for (int s=1;s<256;s<<=1){
    int x = (t>=s) ? buf[t-s] : 0;
    __syncthreads();
    buf[t] += x;
    __syncthreads();
  }
  int ex = partials[blockIdx.x] + buf[t] - v;
  if (i<NN){ off[i]=ex; cursor[i]=ex; }
}

__global__ void scatter_kernel(const int* __restrict__ ei, int* __restrict__ cursor,
                               int* __restrict__ csr_src){
  int e = blockIdx.x*256 + threadIdx.x;
  if (e < NE){
    int d = ei[NE + e];
    int slot = atomicAdd(&cursor[d], 1);
    csr_src[slot] = ei[e];
  }
}

// ---------------- GEMM: out(bf16) = A(bf16,[M,K]) @ B(bf16,[K,Nc]) + bias ----------------
template<int K>
__global__ __launch_bounds__(256) void gemm_bias(const bf16* __restrict__ A,
    const bf16* __restrict__ B, const bf16* __restrict__ bias,
    bf16* __restrict__ outp, int Mrows, int Nc)
{
  __shared__ float Ast[K][65];   // transposed: Ast[k][row]
  __shared__ float Bs[K][64];
  const int tid = threadIdx.x;
  const int r0 = blockIdx.x*64, c0 = blockIdx.y*64;

  for (int idx = tid; idx < 64*K/2; idx += 256){
    int flat = idx*2; int r = flat / K; int k = flat % K;
    int row = r0 + r;
    unsigned int u = 0;
    if (row < Mrows) u = *(const unsigned int*)(A + (size_t)row*K + k);
    Ast[k][r]   = __uint_as_float(u << 16);
    Ast[k+1][r] = __uint_as_float(u & 0xffff0000u);
  }
  for (int idx = tid; idx < K*64/2; idx += 256){
    int flat = idx*2; int k = flat / 64; int c = flat % 64;
    int col = c0 + c;
    unsigned int u = 0;
    if (col + 1 < Nc) u = *(const unsigned int*)(B + (size_t)k*Nc + col);
    Bs[k][c]   = __uint_as_float(u << 16);
    Bs[k][c+1] = __uint_as_float(u & 0xffff0000u);
  }
  __syncthreads();

  int tx = tid & 15, ty = tid >> 4;
  float acc[4][4] = {};
  #pragma unroll 4
  for (int k=0;k<K;++k){
    float a[4], b[4];
    #pragma unroll
    for (int i=0;i<4;++i) a[i] = Ast[k][ty*4+i];
    #pragma unroll
    for (int j=0;j<4;++j) b[j] = Bs[k][tx*4+j];
    #pragma unroll
    for (int i=0;i<4;++i)
      #pragma unroll
      for (int j=0;j<4;++j)
        acc[i][j] += a[i]*b[j];
  }
  #pragma unroll
  for (int i=0;i<4;++i){
    int row = r0 + ty*4 + i;
    if (row >= Mrows) continue;
    #pragma unroll
    for (int j=0;j<4;++j){
      int col = c0 + tx*4 + j;
      if (col >= Nc) continue;
      outp[(size_t)row*Nc + col] = f2b(acc[i][j] + b2f(bias[col]));
    }
  }
}

// ---------------- per-node attention logits ----------------
__global__ void logits_kernel(const bf16* __restrict__ M, const bf16* __restrict__ att,
                              float* __restrict__ L, int C){
  int t = blockIdx.x*256 + threadIdx.x;
  if (t >= NN*NHEADS) return;
  int n = t >> 2, h = t & 3;
  const bf16* row = M + (size_t)n*NHEADS*C + h*C;
  const bf16* av  = att + h*C;
  float acc = 0.f;
  for (int c=0;c<C;++c) acc += b2f(row[c]) * b2f(av[c]);
  L[t] = (acc >= 0.f) ? acc : 0.2f*acc;
}

// ---------------- conv aggregation: one wave per dst node ----------------
template<int C>
__global__ __launch_bounds__(256) void conv_agg(const int* __restrict__ off,
    const int* __restrict__ csr_src, const float* __restrict__ L,
    const bf16* __restrict__ Mmsg, const bf16* __restrict__ Hself,
    bf16* __restrict__ Hout)
{
  constexpr int R = 4*C;
  __shared__ float red[4][R];
  const int wave = threadIdx.x >> 6, lane = threadIdx.x & 63;
  const int n = blockIdx.x*4 + wave;
  const int e0 = off[n], e1 = off[n+1];

  // phase A: segment max of logits
  float4 m4 = make_float4(-INFINITY,-INFINITY,-INFINITY,-INFINITY);
  for (int i=e0+lane; i<e1; i+=64){
    int s = csr_src[i];
    float4 l4 = *(const float4*)(L + 4*(size_t)s);
    m4.x=fmaxf(m4.x,l4.x); m4.y=fmaxf(m4.y,l4.y); m4.z=fmaxf(m4.z,l4.z); m4.w=fmaxf(m4.w,l4.w);
  }
  m4.x=wave_max_f(m4.x); m4.y=wave_max_f(m4.y); m4.z=wave_max_f(m4.z); m4.w=wave_max_f(m4.w);

  // phase B: denom
  float4 dn = make_float4(0,0,0,0);
  for (int i=e0+lane; i<e1; i+=64){
    int s = csr_src[i];
    float4 l4 = *(const float4*)(L + 4*(size_t)s);
    dn.x += __expf(l4.x-m4.x); dn.y += __expf(l4.y-m4.y);
    dn.z += __expf(l4.z-m4.z); dn.w += __expf(l4.w-m4.w);
  }
  dn.x=wave_sum_f(dn.x); dn.y=wave_sum_f(dn.y); dn.z=wave_sum_f(dn.z); dn.w=wave_sum_f(dn.w);
  float4 rden = make_float4(1.f/(dn.x+1e-16f), 1.f/(dn.y+1e-16f),
                            1.f/(dn.z+1e-16f), 1.f/(dn.w+1e-16f));

  // phase C: weighted gather-accumulate. lane handles 8 bf16 channels.
  const bool active = (8*lane) < R;
  const int hidx = (8*lane) / C;
  float acc[8] = {0,0,0,0,0,0,0,0};
  for (int e=e0; e<e1; ++e){
    int s = csr_src[e];
    float4 l4 = *(const float4*)(L + 4*(size_t)s);
    float w0 = __expf(l4.x-m4.x)*rden.x;
    float w1 = __expf(l4.y-m4.y)*rden.y;
    float w2 = __expf(l4.z-m4.z)*rden.z;
    float w3 = __expf(l4.w-m4.w)*rden.w;
    float wl = (hidx==0)?w0:(hidx==1)?w1:(hidx==2)?w2:w3;
    if (active){
      const uint4* q = (const uint4*)(Mmsg + (size_t)s*R) + lane;
      uint4 u = *q;
      acc[0] += __uint_as_float(u.x<<16)*wl;  acc[1] += __uint_as_float(u.x&0xffff0000u)*wl;
      acc[2] += __uint_as_float(u.y<<16)*wl;  acc[3] += __uint_as_float(u.y&0xffff0000u)*wl;
      acc[4] += __uint_as_float(u.z<<16)*wl;  acc[5] += __uint_as_float(u.z&0xffff0000u)*wl;
      acc[6] += __uint_as_float(u.w<<16)*wl;  acc[7] += __uint_as_float(u.w&0xffff0000u)*wl;
    }
  }
  if (active){
    #pragma unroll
    for (int j=0;j<8;++j) red[wave][8*lane+j] = acc[j];
  }
  __syncthreads();

  // epilogue: mean over heads + self (in-place safe: one thread per element)
  for (int c=lane; c<C; c+=64){
    float v = 0.25f*(red[wave][c] + red[wave][C+c] + red[wave][2*C+c] + red[wave][3*C+c]);
    float sv = b2f(Hself[(size_t)n*C + c]);
    Hout[(size_t)n*C + c] = f2b(v + sv);
  }
}

// ---------------- global mean pool ----------------
__global__ __launch_bounds__(256) void pool_kernel(const bf16* __restrict__ H3,
    const int* __restrict__ batch, float* __restrict__ pooled){
  int g = blockIdx.x;
  __shared__ int sb[2];
  if (threadIdx.x < 2){
    int target = g + threadIdx.x;
    int lo=0, hi=NN;
    while (lo<hi){ int mid=(lo+hi)>>1; if (batch[mid]<target) lo=mid+1; else hi=mid; }
    sb[threadIdx.x]=lo;
  }
  __syncthreads();
  int start=sb[0], end=sb[1];
  int c = threadIdx.x & 63, rg = threadIdx.x >> 6;
  float acc=0.f;
  for (int r=start+rg; r<end; r+=4) acc += b2f(H3[(size_t)r*CC3 + c]);
  __shared__ float red[256];
  red[threadIdx.x]=acc; __syncthreads();
  if (threadIdx.x < 64){
    float s = red[c]+red[64+c]+red[128+c]+red[192+c];
    float cnt = (float)(end-start);
    pooled[g*CC3 + c] = s / fmaxf(cnt, 1.0f);
  }
}

// ---------------- classifier + log_softmax (f32 output) ----------------
__global__ __launch_bounds__(64) void fc_kernel(const float* __restrict__ pooled,
    const bf16* __restrict__ Wfc, const bf16* __restrict__ bfc, float* __restrict__ out){
  int g = blockIdx.x, t = threadIdx.x;
  __shared__ float p[CC3];
  __shared__ float lg[NOUT];
  p[t] = pooled[g*CC3 + t];
  __syncthreads();
  if (t < NOUT){
    float a = b2f(bfc[t]);
    for (int c=0;c<CC3;++c) a += p[c]*b2f(Wfc[c*NOUT + t]);
    lg[t] = a;
  }
  __syncthreads();
  if (t < NOUT){
    float m = -INFINITY;
    #pragma unroll
    for (int i=0;i<NOUT;++i) m = fmaxf(m, lg[i]);
    float s = 0.f;
    #pragma unroll
    for (int i=0;i<NOUT;++i) s += __expf(lg[i]-m);
    out[g*NOUT + t] = lg[t] - m - __logf(s);
  }
}

extern "C" void kernel_launch(void* const* d_in, const int* in_sizes, int n_in,
                              void* d_out, int out_size, void* d_ws, size_t ws_size,
                              hipStream_t stream) {
  const float* xf    = (const float*)d_in[0];
  const int*   ei    = (const int*)d_in[1];
  const int*   batch = (const int*)d_in[2];
  const float* pWm1  = (const float*)d_in[3];
  const float* pbm1  = (const float*)d_in[4];
  const float* patt1 = (const float*)d_in[5];
  const float* pWs1  = (const float*)d_in[6];
  const float* pbs1  = (const float*)d_in[7];
  const float* pWm2  = (const float*)d_in[8];
  const float* pbm2  = (const float*)d_in[9];
  const float* patt2 = (const float*)d_in[10];
  const float* pWm3  = (const float*)d_in[11];
  const float* pbm3  = (const float*)d_in[12];
  const float* patt3 = (const float*)d_in[13];
  const float* pWs3  = (const float*)d_in[14];
  const float* pbs3  = (const float*)d_in[15];
  const float* pWfc  = (const float*)d_in[16];
  const float* pbfc  = (const float*)d_in[17];

  // ---- workspace layout (~68 MB), lifetime-aliased ----
  char* p = (char*)d_ws;
  auto alloc = [&](size_t bytes)->char*{ char* q = p; p += (bytes + 255) & ~(size_t)255; return q; };
  int*   deg     = (int*)  alloc(NN*sizeof(int));
  int*   off     = (int*)  alloc((NN+1)*sizeof(int));
  int*   cursor  = (int*)  alloc(NN*sizeof(int));
  int*   csr_src = (int*)  alloc(NE*sizeof(int));
  int*   partials= (int*)  alloc(NPART*sizeof(int));
  float* L       = (float*)alloc((size_t)NN*4*sizeof(float));
  bf16*  Mb      = (bf16*) alloc((size_t)NN*384*sizeof(bf16));   // 38.4 MB, reused per layer
  bf16*  H1b     = (bf16*) alloc((size_t)NN*96*sizeof(bf16));    // 9.6 MB; H3 aliases this
  bf16*  H2b     = (bf16*) alloc((size_t)NN*96*sizeof(bf16));    // 9.6 MB
  float* pooled  = (float*)alloc((size_t)NG*CC3*sizeof(float));
  bf16*  xb      = (bf16*) alloc((size_t)NN*FIN*sizeof(bf16));   // 6.4 MB
  bf16*  Wm1 = (bf16*)alloc(FIN*384*sizeof(bf16));
  bf16*  bm1 = (bf16*)alloc(384*sizeof(bf16));
  bf16*  att1= (bf16*)alloc(384*sizeof(bf16));
  bf16*  Ws1 = (bf16*)alloc(FIN*96*sizeof(bf16));
  bf16*  bs1 = (bf16*)alloc(96*sizeof(bf16));
  bf16*  Wm2 = (bf16*)alloc(HID*384*sizeof(bf16));
  bf16*  bm2 = (bf16*)alloc(384*sizeof(bf16));
  bf16*  att2= (bf16*)alloc(384*sizeof(bf16));
  bf16*  Wm3 = (bf16*)alloc(HID*256*sizeof(bf16));
  bf16*  bm3 = (bf16*)alloc(256*sizeof(bf16));
  bf16*  att3= (bf16*)alloc(256*sizeof(bf16));
  bf16*  Ws3 = (bf16*)alloc(HID*64*sizeof(bf16));
  bf16*  bs3 = (bf16*)alloc(64*sizeof(bf16));
  bf16*  Wfc = (bf16*)alloc(CC3*NOUT*sizeof(bf16));
  bf16*  bfc = (bf16*)alloc(NOUT*sizeof(bf16));
  bf16*  H3b = H1b;   // H1 dead after layer-2 aggregation (stream-ordered)

  // ---- prologue: cast f32 -> bf16 ----
  CastJobs cj;
  int ji = 0;
  auto addj = [&](const float* s, bf16* d, int n){ cj.src[ji]=s; cj.dst[ji]=d; cj.n[ji]=n; ++ji; };
  addj(xf,   xb,   NN*FIN);
  addj(pWm1, Wm1,  FIN*384); addj(pbm1, bm1, 384); addj(patt1, att1, 384);
  addj(pWs1, Ws1,  FIN*96);  addj(pbs1, bs1, 96);
  addj(pWm2, Wm2,  HID*384); addj(pbm2, bm2, 384); addj(patt2, att2, 384);
  addj(pWm3, Wm3,  HID*256); addj(pbm3, bm3, 256); addj(patt3, att3, 256);
  addj(pWs3, Ws3,  HID*64);  addj(pbs3, bs3, 64);
  addj(pWfc, Wfc,  CC3*NOUT); addj(pbfc, bfc, NOUT);
  cast_kernel<<<2048, 256, 0, stream>>>(cj);

  // ---- CSR build (hierarchical scan; reused by all 3 layers) ----
  hipMemsetAsync(deg, 0, NN*sizeof(int), stream);
  deg_kernel<<<(NE+255)/256, 256, 0, stream>>>(ei, deg);
  scan_part_kernel<<<NPART, 256, 0, stream>>>(deg, partials);
  scan_top_kernel<<<1, 256, 0, stream>>>(partials, off);
  scan_final_kernel<<<NPART, 256, 0, stream>>>(deg, partials, off, cursor);
  scatter_kernel<<<(NE+255)/256, 256, 0, stream>>>(ei, cursor, csr_src);

  const int RB = (NN + 63)/64;            // 782 row blocks
  const int LB = (NN*4 + 255)/256;        // logits blocks
  const int AB = NN/4;                    // 12500 agg blocks (4 waves each)

  // ---- layer 1: FIN=64 -> HID=96 ----
  gemm_bias<64><<<dim3(RB,2), 256, 0, stream>>>(xb, Ws1, bs1, H1b, NN, 96);  // self pre-fill
  gemm_bias<64><<<dim3(RB,6), 256, 0, stream>>>(xb, Wm1, bm1, Mb, NN, 384);
  logits_kernel<<<LB, 256, 0, stream>>>(Mb, att1, L, 96);
  conv_agg<96><<<AB, 256, 0, stream>>>(off, csr_src, L, Mb, H1b, H1b);       // in-place += agg

  // ---- layer 2: HID -> HID (identity self) ----
  gemm_bias<96><<<dim3(RB,6), 256, 0, stream>>>(H1b, Wm2, bm2, Mb, NN, 384);
  logits_kernel<<<LB, 256, 0, stream>>>(Mb, att2, L, 96);
  conv_agg<96><<<AB, 256, 0, stream>>>(off, csr_src, L, Mb, H1b, H2b);

  // ---- layer 3: HID -> CC3=64 ----
  gemm_bias<96><<<dim3(RB,4), 256, 0, stream>>>(H2b, Wm3, bm3, Mb, NN, 256);
  gemm_bias<96><<<dim3(RB,1), 256, 0, stream>>>(H2b, Ws3, bs3, H3b, NN, 64); // self pre-fill (over H1)
  logits_kernel<<<LB, 256, 0, stream>>>(Mb, att3, L, 64);
  conv_agg<64><<<AB, 256, 0, stream>>>(off, csr_src, L, Mb, H3b, H3b);       // in-place += agg

  // ---- pool + classifier ----
  pool_kernel<<<NG, 256, 0, stream>>>(H3b, batch, pooled);
  fc_kernel<<<NG, 64, 0, stream>>>(pooled, Wfc, bfc, (float*)d_out);
}

// Round 6
// 686.726 us; speedup vs baseline: 2.1114x; 1.5760x over previous
//
#include <hip/hip_runtime.h>
#include <hip/hip_bf16.h>
#include <stdint.h>

using bf16 = __hip_bfloat16;
typedef __attribute__((ext_vector_type(8))) short bf16x8;
typedef __attribute__((ext_vector_type(4))) float f32x4;

#define NN 50000
#define NE 400000
#define NG 64
#define NHEADS 4
#define FIN 64
#define HID 96
#define CC3 64
#define NOUT 10

#define SCAN_BLOCK 256
#define NPART ((NN + SCAN_BLOCK - 1) / SCAN_BLOCK)   // 196 (<=256)

__device__ __forceinline__ float b2f(bf16 h){ return __bfloat162float(h); }
__device__ __forceinline__ bf16 f2b(float f){ return __float2bfloat16(f); }

__device__ __forceinline__ float wave_max_f(float v){
  #pragma unroll
  for (int m=1;m<64;m<<=1) v = fmaxf(v, __shfl_xor(v,m));
  return v;
}
__device__ __forceinline__ float wave_sum_f(float v){
  #pragma unroll
  for (int m=1;m<64;m<<=1) v += __shfl_xor(v,m);
  return v;
}

// ---------------- prologue: cast f32 inputs -> bf16 copies ----------------
#define NJOBS 11
struct CastJobs {
  const float* src[NJOBS];
  bf16*        dst[NJOBS];
  int          n[NJOBS];
};
__global__ __launch_bounds__(256) void cast_kernel(CastJobs j){
  for (int t=0; t<NJOBS; ++t){
    int n = j.n[t];
    const float* s = j.src[t];
    bf16* d = j.dst[t];
    for (int i = blockIdx.x*256 + threadIdx.x; i < n; i += gridDim.x*256)
      d[i] = f2b(s[i]);
  }
}

// ---------------- prologue: transpose weights f32[K,Nc] -> bf16 WT[Nc,K] ----------------
#define NTJOBS 5
struct TransJobs {
  const float* W[NTJOBS];
  bf16*        WT[NTJOBS];
  int          K[NTJOBS];
  int          Nc[NTJOBS];
};
__global__ __launch_bounds__(256) void trans_kernel(TransJobs j){
  for (int t=0; t<NTJOBS; ++t){
    int K = j.K[t], Nc = j.Nc[t], total = K*Nc;
    for (int i = blockIdx.x*256 + threadIdx.x; i < total; i += gridDim.x*256){
      int k = i / Nc, n = i % Nc;
      j.WT[t][(size_t)n*K + k] = f2b(j.W[t][i]);
    }
  }
}

// ---------------- CSR build ----------------
__global__ void deg_kernel(const int* __restrict__ ei, int* __restrict__ deg){
  int e = blockIdx.x*256 + threadIdx.x;
  if (e < NE) atomicAdd(&deg[ei[NE + e]], 1);
}

__global__ __launch_bounds__(256) void scan_part_kernel(const int* __restrict__ deg,
                                                        int* __restrict__ partials){
  int i = blockIdx.x*SCAN_BLOCK + threadIdx.x;
  int v = (i < NN) ? deg[i] : 0;
  __shared__ int ws[4];
  int lane = threadIdx.x & 63, w = threadIdx.x >> 6;
  int s = v;
  #pragma unroll
  for (int m=1;m<64;m<<=1) s += __shfl_xor(s,m);
  if (lane==0) ws[w]=s;
  __syncthreads();
  if (threadIdx.x==0) partials[blockIdx.x] = ws[0]+ws[1]+ws[2]+ws[3];
}

__global__ __launch_bounds__(256) void scan_top_kernel(int* __restrict__ partials,
                                                       int* __restrict__ off){
  __shared__ int buf[256];
  int t = threadIdx.x;
  int v = (t < NPART) ? partials[t] : 0;
  buf[t] = v; __syncthreads();
  for (int s=1;s<256;s<<=1){
    int x = (t>=s) ? buf[t-s] : 0;
    __syncthreads();
    buf[t] += x;
    __syncthreads();
  }
  if (t < NPART) partials[t] = buf[t] - v;   // exclusive
  if (t == 0) off[NN] = buf[255];
}

__global__ __launch_bounds__(256) void scan_final_kernel(const int* __restrict__ deg,
    const int* __restrict__ partials, int* __restrict__ off, int* __restrict__ cursor){
  __shared__ int buf[256];
  int i = blockIdx.x*SCAN_BLOCK + threadIdx.x;
  int t = threadIdx.x;
  int v = (i<NN) ? deg[i] : 0;
  buf[t] = v; __syncthreads();
  for (int s=1;s<256;s<<=1){
    int x = (t>=s) ? buf[t-s] : 0;
    __syncthreads();
    buf[t] += x;
    __syncthreads();
  }
  int ex = partials[blockIdx.x] + buf[t] - v;
  if (i<NN){ off[i]=ex; cursor[i]=ex; }
}

__global__ void scatter_kernel(const int* __restrict__ ei, int* __restrict__ cursor,
                               int* __restrict__ csr_src){
  int e = blockIdx.x*256 + threadIdx.x;
  if (e < NE){
    int d = ei[NE + e];
    int slot = atomicAdd(&cursor[d], 1);
    csr_src[slot] = ei[e];
  }
}

// ---------------- MFMA GEMM: out[M,Nc](bf16) = A[M,K](bf16) @ W + bias ----------------
// W supplied TRANSPOSED: WT[Nc,K]. A-frag & B-frag are both contiguous 16B/lane loads:
//   A: lane l -> A[r0+i*16+(l&15)][kt*32+(l>>4)*8 .. +7]
//   B: lane l -> WT[c0+t*16+(l&15)][kt*32+(l>>4)*8 .. +7]
// D layout (m89-verified): col=lane&15, row=(lane>>4)*4+reg.
// block = 4 waves, tile 128 rows x 64 cols; wave tile 32x64.
template<int K>
__global__ __launch_bounds__(256) void gemm_mfma(const bf16* __restrict__ A,
    const bf16* __restrict__ WT, const bf16* __restrict__ bias,
    bf16* __restrict__ out, int Mrows, int Nc)
{
  const int wave = threadIdx.x >> 6, lane = threadIdx.x & 63;
  const int r0 = blockIdx.x*128 + wave*32;
  const int c0 = blockIdx.y*64;
  const int lm = lane & 15, q = lane >> 4;

  f32x4 acc[2][4] = {};
  const bf16x8 zfrag = {0,0,0,0,0,0,0,0};

  #pragma unroll
  for (int kt=0; kt<K/32; ++kt){
    const int kk = kt*32 + q*8;
    bf16x8 afrag[2];
    #pragma unroll
    for (int i=0;i<2;++i){
      int row = r0 + i*16 + lm;
      afrag[i] = (row < Mrows) ? *(const bf16x8*)(A + (size_t)row*K + kk) : zfrag;
    }
    #pragma unroll
    for (int t=0;t<4;++t){
      int col = c0 + t*16 + lm;
      bf16x8 bfrag = (col < Nc) ? *(const bf16x8*)(WT + (size_t)col*K + kk) : zfrag;
      #pragma unroll
      for (int i=0;i<2;++i)
        acc[i][t] = __builtin_amdgcn_mfma_f32_16x16x32_bf16(afrag[i], bfrag, acc[i][t], 0,0,0);
    }
  }

  #pragma unroll
  for (int t=0;t<4;++t){
    int col = c0 + t*16 + lm;
    if (col >= Nc) continue;
    float bv = b2f(bias[col]);
    #pragma unroll
    for (int i=0;i<2;++i){
      #pragma unroll
      for (int r=0;r<4;++r){
        int row = r0 + i*16 + q*4 + r;
        if (row < Mrows) out[(size_t)row*Nc + col] = f2b(acc[i][t][r] + bv);
      }
    }
  }
}

// ---------------- per-node attention logits (uint4-vectorized) ----------------
__global__ void logits_kernel(const bf16* __restrict__ M, const bf16* __restrict__ att,
                              float* __restrict__ L, int C){
  int t = blockIdx.x*256 + threadIdx.x;
  if (t >= NN*NHEADS) return;
  int n = t >> 2, h = t & 3;
  const uint4* row = (const uint4*)(M + (size_t)n*NHEADS*C + h*C);
  const uint4* av  = (const uint4*)(att + h*C);
  float acc = 0.f;
  for (int c8=0; c8<C/8; ++c8){
    uint4 u = row[c8], a = av[c8];
    acc += __uint_as_float(u.x<<16)*__uint_as_float(a.x<<16)
         + __uint_as_float(u.x&0xffff0000u)*__uint_as_float(a.x&0xffff0000u)
         + __uint_as_float(u.y<<16)*__uint_as_float(a.y<<16)
         + __uint_as_float(u.y&0xffff0000u)*__uint_as_float(a.y&0xffff0000u)
         + __uint_as_float(u.z<<16)*__uint_as_float(a.z<<16)
         + __uint_as_float(u.z&0xffff0000u)*__uint_as_float(a.z&0xffff0000u)
         + __uint_as_float(u.w<<16)*__uint_as_float(a.w<<16)
         + __uint_as_float(u.w&0xffff0000u)*__uint_as_float(a.w&0xffff0000u);
  }
  L[t] = (acc >= 0.f) ? acc : 0.2f*acc;
}

// ---------------- conv aggregation: one wave per dst node ----------------
template<int C>
__global__ __launch_bounds__(256) void conv_agg(const int* __restrict__ off,
    const int* __restrict__ csr_src, const float* __restrict__ L,
    const bf16* __restrict__ Mmsg, const bf16* __restrict__ Hself,
    bf16* __restrict__ Hout)
{
  constexpr int R = 4*C;
  __shared__ float red[4][R];
  const int wave = threadIdx.x >> 6, lane = threadIdx.x & 63;
  const int n = blockIdx.x*4 + wave;
  const int e0 = off[n], e1 = off[n+1];

  // phase A: segment max of logits
  float4 m4 = make_float4(-INFINITY,-INFINITY,-INFINITY,-INFINITY);
  for (int i=e0+lane; i<e1; i+=64){
    int s = csr_src[i];
    float4 l4 = *(const float4*)(L + 4*(size_t)s);
    m4.x=fmaxf(m4.x,l4.x); m4.y=fmaxf(m4.y,l4.y); m4.z=fmaxf(m4.z,l4.z); m4.w=fmaxf(m4.w,l4.w);
  }
  m4.x=wave_max_f(m4.x); m4.y=wave_max_f(m4.y); m4.z=wave_max_f(m4.z); m4.w=wave_max_f(m4.w);

  // phase B: denom
  float4 dn = make_float4(0,0,0,0);
  for (int i=e0+lane; i<e1; i+=64){
    int s = csr_src[i];
    float4 l4 = *(const float4*)(L + 4*(size_t)s);
    dn.x += __expf(l4.x-m4.x); dn.y += __expf(l4.y-m4.y);
    dn.z += __expf(l4.z-m4.z); dn.w += __expf(l4.w-m4.w);
  }
  dn.x=wave_sum_f(dn.x); dn.y=wave_sum_f(dn.y); dn.z=wave_sum_f(dn.z); dn.w=wave_sum_f(dn.w);
  float4 rden = make_float4(1.f/(dn.x+1e-16f), 1.f/(dn.y+1e-16f),
                            1.f/(dn.z+1e-16f), 1.f/(dn.w+1e-16f));

  // phase C: weighted gather-accumulate. lane handles 8 bf16 channels.
  const bool active = (8*lane) < R;
  const int hidx = (8*lane) / C;
  float acc[8] = {0,0,0,0,0,0,0,0};
  for (int e=e0; e<e1; ++e){
    int s = csr_src[e];
    float4 l4 = *(const float4*)(L + 4*(size_t)s);
    float w0 = __expf(l4.x-m4.x)*rden.x;
    float w1 = __expf(l4.y-m4.y)*rden.y;
    float w2 = __expf(l4.z-m4.z)*rden.z;
    float w3 = __expf(l4.w-m4.w)*rden.w;
    float wl = (hidx==0)?w0:(hidx==1)?w1:(hidx==2)?w2:w3;
    if (active){
      const uint4* qp = (const uint4*)(Mmsg + (size_t)s*R) + lane;
      uint4 u = *qp;
      acc[0] += __uint_as_float(u.x<<16)*wl;  acc[1] += __uint_as_float(u.x&0xffff0000u)*wl;
      acc[2] += __uint_as_float(u.y<<16)*wl;  acc[3] += __uint_as_float(u.y&0xffff0000u)*wl;
      acc[4] += __uint_as_float(u.z<<16)*wl;  acc[5] += __uint_as_float(u.z&0xffff0000u)*wl;
      acc[6] += __uint_as_float(u.w<<16)*wl;  acc[7] += __uint_as_float(u.w&0xffff0000u)*wl;
    }
  }
  if (active){
    #pragma unroll
    for (int j=0;j<8;++j) red[wave][8*lane+j] = acc[j];
  }
  __syncthreads();

  // epilogue: mean over heads + self (in-place safe: one thread per element)
  for (int c=lane; c<C; c+=64){
    float v = 0.25f*(red[wave][c] + red[wave][C+c] + red[wave][2*C+c] + red[wave][3*C+c]);
    float sv = b2f(Hself[(size_t)n*C + c]);
    Hout[(size_t)n*C + c] = f2b(v + sv);
  }
}

// ---------------- global mean pool ----------------
__global__ __launch_bounds__(256) void pool_kernel(const bf16* __restrict__ H3,
    const int* __restrict__ batch, float* __restrict__ pooled){
  int g = blockIdx.x;
  __shared__ int sb[2];
  if (threadIdx.x < 2){
    int target = g + threadIdx.x;
    int lo=0, hi=NN;
    while (lo<hi){ int mid=(lo+hi)>>1; if (batch[mid]<target) lo=mid+1; else hi=mid; }
    sb[threadIdx.x]=lo;
  }
  __syncthreads();
  int start=sb[0], end=sb[1];
  int c = threadIdx.x & 63, rg = threadIdx.x >> 6;
  float acc=0.f;
  for (int r=start+rg; r<end; r+=4) acc += b2f(H3[(size_t)r*CC3 + c]);
  __shared__ float red[256];
  red[threadIdx.x]=acc; __syncthreads();
  if (threadIdx.x < 64){
    float s = red[c]+red[64+c]+red[128+c]+red[192+c];
    float cnt = (float)(end-start);
    pooled[g*CC3 + c] = s / fmaxf(cnt, 1.0f);
  }
}

// ---------------- classifier + log_softmax (f32 output) ----------------
__global__ __launch_bounds__(64) void fc_kernel(const float* __restrict__ pooled,
    const bf16* __restrict__ Wfc, const bf16* __restrict__ bfc, float* __restrict__ out){
  int g = blockIdx.x, t = threadIdx.x;
  __shared__ float p[CC3];
  __shared__ float lg[NOUT];
  p[t] = pooled[g*CC3 + t];
  __syncthreads();
  if (t < NOUT){
    float a = b2f(bfc[t]);
    for (int c=0;c<CC3;++c) a += p[c]*b2f(Wfc[c*NOUT + t]);
    lg[t] = a;
  }
  __syncthreads();
  if (t < NOUT){
    float m = -INFINITY;
    #pragma unroll
    for (int i=0;i<NOUT;++i) m = fmaxf(m, lg[i]);
    float s = 0.f;
    #pragma unroll
    for (int i=0;i<NOUT;++i) s += __expf(lg[i]-m);
    out[g*NOUT + t] = lg[t] - m - __logf(s);
  }
}

extern "C" void kernel_launch(void* const* d_in, const int* in_sizes, int n_in,
                              void* d_out, int out_size, void* d_ws, size_t ws_size,
                              hipStream_t stream) {
  const float* xf    = (const float*)d_in[0];
  const int*   ei    = (const int*)d_in[1];
  const int*   batch = (const int*)d_in[2];
  const float* pWm1  = (const float*)d_in[3];
  const float* pbm1  = (const float*)d_in[4];
  const float* patt1 = (const float*)d_in[5];
  const float* pWs1  = (const float*)d_in[6];
  const float* pbs1  = (const float*)d_in[7];
  const float* pWm2  = (const float*)d_in[8];
  const float* pbm2  = (const float*)d_in[9];
  const float* patt2 = (const float*)d_in[10];
  const float* pWm3  = (const float*)d_in[11];
  const float* pbm3  = (const float*)d_in[12];
  const float* patt3 = (const float*)d_in[13];
  const float* pWs3  = (const float*)d_in[14];
  const float* pbs3  = (const float*)d_in[15];
  const float* pWfc  = (const float*)d_in[16];
  const float* pbfc  = (const float*)d_in[17];

  // ---- workspace layout, lifetime-aliased ----
  char* p = (char*)d_ws;
  auto alloc = [&](size_t bytes)->char*{ char* q = p; p += (bytes + 255) & ~(size_t)255; return q; };
  int*   deg     = (int*)  alloc(NN*sizeof(int));
  int*   off     = (int*)  alloc((NN+1)*sizeof(int));
  int*   cursor  = (int*)  alloc(NN*sizeof(int));
  int*   csr_src = (int*)  alloc(NE*sizeof(int));
  int*   partials= (int*)  alloc(NPART*sizeof(int));
  float* L       = (float*)alloc((size_t)NN*4*sizeof(float));
  bf16*  Mb      = (bf16*) alloc((size_t)NN*384*sizeof(bf16));   // 38.4 MB, reused per layer
  bf16*  H1b     = (bf16*) alloc((size_t)NN*96*sizeof(bf16));    // 9.6 MB; H3 aliases this
  bf16*  H2b     = (bf16*) alloc((size_t)NN*96*sizeof(bf16));    // 9.6 MB
  float* pooled  = (float*)alloc((size_t)NG*CC3*sizeof(float));
  bf16*  xb      = (bf16*) alloc((size_t)NN*FIN*sizeof(bf16));   // 6.4 MB
  // transposed bf16 weights [Nc,K]
  bf16*  Wm1T = (bf16*)alloc(384*FIN*sizeof(bf16));
  bf16*  Ws1T = (bf16*)alloc(96*FIN*sizeof(bf16));
  bf16*  Wm2T = (bf16*)alloc(384*HID*sizeof(bf16));
  bf16*  Wm3T = (bf16*)alloc(256*HID*sizeof(bf16));
  bf16*  Ws3T = (bf16*)alloc(64*HID*sizeof(bf16));
  // small bf16 casts
  bf16*  bm1 = (bf16*)alloc(384*sizeof(bf16));
  bf16*  att1= (bf16*)alloc(384*sizeof(bf16));
  bf16*  bs1 = (bf16*)alloc(96*sizeof(bf16));
  bf16*  bm2 = (bf16*)alloc(384*sizeof(bf16));
  bf16*  att2= (bf16*)alloc(384*sizeof(bf16));
  bf16*  bm3 = (bf16*)alloc(256*sizeof(bf16));
  bf16*  att3= (bf16*)alloc(256*sizeof(bf16));
  bf16*  bs3 = (bf16*)alloc(64*sizeof(bf16));
  bf16*  Wfc = (bf16*)alloc(CC3*NOUT*sizeof(bf16));
  bf16*  bfc = (bf16*)alloc(NOUT*sizeof(bf16));
  bf16*  H3b = H1b;   // H1 dead after layer-2 aggregation (stream-ordered)

  // ---- prologue: casts + weight transposes ----
  CastJobs cj;
  int ji = 0;
  auto addj = [&](const float* s, bf16* d, int n){ cj.src[ji]=s; cj.dst[ji]=d; cj.n[ji]=n; ++ji; };
  addj(xf,   xb,   NN*FIN);
  addj(pbm1, bm1, 384); addj(patt1, att1, 384); addj(pbs1, bs1, 96);
  addj(pbm2, bm2, 384); addj(patt2, att2, 384);
  addj(pbm3, bm3, 256); addj(patt3, att3, 256); addj(pbs3, bs3, 64);
  addj(pWfc, Wfc,  CC3*NOUT); addj(pbfc, bfc, NOUT);
  cast_kernel<<<2048, 256, 0, stream>>>(cj);

  TransJobs tj;
  tj.W[0]=pWm1; tj.WT[0]=Wm1T; tj.K[0]=FIN; tj.Nc[0]=384;
  tj.W[1]=pWs1; tj.WT[1]=Ws1T; tj.K[1]=FIN; tj.Nc[1]=96;
  tj.W[2]=pWm2; tj.WT[2]=Wm2T; tj.K[2]=HID; tj.Nc[2]=384;
  tj.W[3]=pWm3; tj.WT[3]=Wm3T; tj.K[3]=HID; tj.Nc[3]=256;
  tj.W[4]=pWs3; tj.WT[4]=Ws3T; tj.K[4]=HID; tj.Nc[4]=64;
  trans_kernel<<<256, 256, 0, stream>>>(tj);

  // ---- CSR build (hierarchical scan; reused by all 3 layers) ----
  hipMemsetAsync(deg, 0, NN*sizeof(int), stream);
  deg_kernel<<<(NE+255)/256, 256, 0, stream>>>(ei, deg);
  scan_part_kernel<<<NPART, 256, 0, stream>>>(deg, partials);
  scan_top_kernel<<<1, 256, 0, stream>>>(partials, off);
  scan_final_kernel<<<NPART, 256, 0, stream>>>(deg, partials, off, cursor);
  scatter_kernel<<<(NE+255)/256, 256, 0, stream>>>(ei, cursor, csr_src);

  const int MB128 = (NN + 127)/128;       // 391 row blocks (MFMA)
  const int LB = (NN*4 + 255)/256;        // logits blocks
  const int AB = NN/4;                    // 12500 agg blocks (4 waves each)

  // ---- layer 1: FIN=64 -> HID=96 ----
  gemm_mfma<64><<<dim3(MB128,2), 256, 0, stream>>>(xb, Ws1T, bs1, H1b, NN, 96);  // self pre-fill
  gemm_mfma<64><<<dim3(MB128,6), 256, 0, stream>>>(xb, Wm1T, bm1, Mb, NN, 384);
  logits_kernel<<<LB, 256, 0, stream>>>(Mb, att1, L, 96);
  conv_agg<96><<<AB, 256, 0, stream>>>(off, csr_src, L, Mb, H1b, H1b);           // in-place += agg

  // ---- layer 2: HID -> HID (identity self) ----
  gemm_mfma<96><<<dim3(MB128,6), 256, 0, stream>>>(H1b, Wm2T, bm2, Mb, NN, 384);
  logits_kernel<<<LB, 256, 0, stream>>>(Mb, att2, L, 96);
  conv_agg<96><<<AB, 256, 0, stream>>>(off, csr_src, L, Mb, H1b, H2b);

  // ---- layer 3: HID -> CC3=64 ----
  gemm_mfma<96><<<dim3(MB128,4), 256, 0, stream>>>(H2b, Wm3T, bm3, Mb, NN, 256);
  gemm_mfma<96><<<dim3(MB128,1), 256, 0, stream>>>(H2b, Ws3T, bs3, H3b, NN, 64); // self pre-fill
  logits_kernel<<<LB, 256, 0, stream>>>(Mb, att3, L, 64);
  conv_agg<64><<<AB, 256, 0, stream>>>(off, csr_src, L, Mb, H3b, H3b);           // in-place += agg

  // ---- pool + classifier ----
  pool_kernel<<<NG, 256, 0, stream>>>(H3b, batch, pooled);
  fc_kernel<<<NG, 64, 0, stream>>>(pooled, Wfc, bfc, (float*)d_out);
}

// Round 7
// 594.815 us; speedup vs baseline: 2.4377x; 1.1545x over previous
//
#include <hip/hip_runtime.h>
#include <hip/hip_bf16.h>
#include <stdint.h>

using bf16 = __hip_bfloat16;
typedef __attribute__((ext_vector_type(8))) short bf16x8;
typedef __attribute__((ext_vector_type(4))) float f32x4;

#define NN 50000
#define NE 400000
#define NG 64
#define NHEADS 4
#define FIN 64
#define HID 96
#define CC3 64
#define NOUT 10

#define SCAN_BLOCK 256
#define NPART ((NN + SCAN_BLOCK - 1) / SCAN_BLOCK)   // 196 (<=256)

__device__ __forceinline__ float b2f(bf16 h){ return __bfloat162float(h); }
__device__ __forceinline__ bf16 f2b(float f){ return __float2bfloat16(f); }

// ---------------- prologue: cast f32 inputs -> bf16 copies ----------------
#define NJOBS 11
struct CastJobs {
  const float* src[NJOBS];
  bf16*        dst[NJOBS];
  int          n[NJOBS];
};
__global__ __launch_bounds__(256) void cast_kernel(CastJobs j){
  for (int t=0; t<NJOBS; ++t){
    int n = j.n[t];
    const float* s = j.src[t];
    bf16* d = j.dst[t];
    for (int i = blockIdx.x*256 + threadIdx.x; i < n; i += gridDim.x*256)
      d[i] = f2b(s[i]);
  }
}

// ---------------- prologue: transpose weights f32[K,Nc] -> bf16 WT[Nc,K] ----------------
#define NTJOBS 5
struct TransJobs {
  const float* W[NTJOBS];
  bf16*        WT[NTJOBS];
  int          K[NTJOBS];
  int          Nc[NTJOBS];
};
__global__ __launch_bounds__(256) void trans_kernel(TransJobs j){
  for (int t=0; t<NTJOBS; ++t){
    int K = j.K[t], Nc = j.Nc[t], total = K*Nc;
    for (int i = blockIdx.x*256 + threadIdx.x; i < total; i += gridDim.x*256){
      int k = i / Nc, n = i % Nc;
      j.WT[t][(size_t)n*K + k] = f2b(j.W[t][i]);
    }
  }
}

// ---------------- CSR build ----------------
__global__ void deg_kernel(const int* __restrict__ ei, int* __restrict__ deg){
  int e = blockIdx.x*256 + threadIdx.x;
  if (e < NE) atomicAdd(&deg[ei[NE + e]], 1);
}

__global__ __launch_bounds__(256) void scan_part_kernel(const int* __restrict__ deg,
                                                        int* __restrict__ partials){
  int i = blockIdx.x*SCAN_BLOCK + threadIdx.x;
  int v = (i < NN) ? deg[i] : 0;
  __shared__ int ws[4];
  int lane = threadIdx.x & 63, w = threadIdx.x >> 6;
  int s = v;
  #pragma unroll
  for (int m=1;m<64;m<<=1) s += __shfl_xor(s,m);
  if (lane==0) ws[w]=s;
  __syncthreads();
  if (threadIdx.x==0) partials[blockIdx.x] = ws[0]+ws[1]+ws[2]+ws[3];
}

__global__ __launch_bounds__(256) void scan_top_kernel(int* __restrict__ partials,
                                                       int* __restrict__ off){
  __shared__ int buf[256];
  int t = threadIdx.x;
  int v = (t < NPART) ? partials[t] : 0;
  buf[t] = v; __syncthreads();
  for (int s=1;s<256;s<<=1){
    int x = (t>=s) ? buf[t-s] : 0;
    __syncthreads();
    buf[t] += x;
    __syncthreads();
  }
  if (t < NPART) partials[t] = buf[t] - v;   // exclusive
  if (t == 0) off[NN] = buf[255];
}

__global__ __launch_bounds__(256) void scan_final_kernel(const int* __restrict__ deg,
    const int* __restrict__ partials, int* __restrict__ off, int* __restrict__ cursor){
  __shared__ int buf[256];
  int i = blockIdx.x*SCAN_BLOCK + threadIdx.x;
  int t = threadIdx.x;
  int v = (i<NN) ? deg[i] : 0;
  buf[t] = v; __syncthreads();
  for (int s=1;s<256;s<<=1){
    int x = (t>=s) ? buf[t-s] : 0;
    __syncthreads();
    buf[t] += x;
    __syncthreads();
  }
  int ex = partials[blockIdx.x] + buf[t] - v;
  if (i<NN){ off[i]=ex; cursor[i]=ex; }
}

__global__ void scatter_kernel(const int* __restrict__ ei, int* __restrict__ cursor,
                               int* __restrict__ csr_src){
  int e = blockIdx.x*256 + threadIdx.x;
  if (e < NE){
    int d = ei[NE + e];
    int slot = atomicAdd(&cursor[d], 1);
    csr_src[slot] = ei[e];
  }
}

// ---------------- MFMA GEMM: out[M,Nc](bf16) = A[M,K](bf16) @ W + bias ----------------
// W supplied TRANSPOSED: WT[Nc,K]. A-frag & B-frag are contiguous 16B/lane loads.
// D layout (m89-verified): col=lane&15, row=(lane>>4)*4+reg.
// block = 4 waves, tile 128 rows x 64 cols; wave tile 32x64.
template<int K>
__global__ __launch_bounds__(256) void gemm_mfma(const bf16* __restrict__ A,
    const bf16* __restrict__ WT, const bf16* __restrict__ bias,
    bf16* __restrict__ out, int Mrows, int Nc)
{
  const int wave = threadIdx.x >> 6, lane = threadIdx.x & 63;
  const int r0 = blockIdx.x*128 + wave*32;
  const int c0 = blockIdx.y*64;
  const int lm = lane & 15, q = lane >> 4;

  f32x4 acc[2][4] = {};
  const bf16x8 zfrag = {0,0,0,0,0,0,0,0};

  #pragma unroll
  for (int kt=0; kt<K/32; ++kt){
    const int kk = kt*32 + q*8;
    bf16x8 afrag[2];
    #pragma unroll
    for (int i=0;i<2;++i){
      int row = r0 + i*16 + lm;
      afrag[i] = (row < Mrows) ? *(const bf16x8*)(A + (size_t)row*K + kk) : zfrag;
    }
    #pragma unroll
    for (int t=0;t<4;++t){
      int col = c0 + t*16 + lm;
      bf16x8 bfrag = (col < Nc) ? *(const bf16x8*)(WT + (size_t)col*K + kk) : zfrag;
      #pragma unroll
      for (int i=0;i<2;++i)
        acc[i][t] = __builtin_amdgcn_mfma_f32_16x16x32_bf16(afrag[i], bfrag, acc[i][t], 0,0,0);
    }
  }

  #pragma unroll
  for (int t=0;t<4;++t){
    int col = c0 + t*16 + lm;
    if (col >= Nc) continue;
    float bv = b2f(bias[col]);
    #pragma unroll
    for (int i=0;i<2;++i){
      #pragma unroll
      for (int r=0;r<4;++r){
        int row = r0 + i*16 + q*4 + r;
        if (row < Mrows) out[(size_t)row*Nc + col] = f2b(acc[i][t][r] + bv);
      }
    }
  }
}

// ---------------- per-node attention exp-logits ----------------
// EL[n,h] = exp(clamp(leaky_relu(sum_c M[n,h*C+c]*att[h,c], 0.2), +-60))
// Max-subtraction dropped: logits are O(1) here (weights scaled 0.05), so
// softmax(l) = exp(l)/sum(exp(l)) exactly; clamp is a never-binding guard.
__global__ void expl_kernel(const bf16* __restrict__ M, const bf16* __restrict__ att,
                            float* __restrict__ EL, int C){
  int t = blockIdx.x*256 + threadIdx.x;
  if (t >= NN*NHEADS) return;
  int n = t >> 2, h = t & 3;
  const uint4* row = (const uint4*)(M + (size_t)n*NHEADS*C + h*C);
  const uint4* av  = (const uint4*)(att + h*C);
  float acc = 0.f;
  for (int c8=0; c8<C/8; ++c8){
    uint4 u = row[c8], a = av[c8];
    acc += __uint_as_float(u.x<<16)*__uint_as_float(a.x<<16)
         + __uint_as_float(u.x&0xffff0000u)*__uint_as_float(a.x&0xffff0000u)
         + __uint_as_float(u.y<<16)*__uint_as_float(a.y<<16)
         + __uint_as_float(u.y&0xffff0000u)*__uint_as_float(a.y&0xffff0000u)
         + __uint_as_float(u.z<<16)*__uint_as_float(a.z<<16)
         + __uint_as_float(u.z&0xffff0000u)*__uint_as_float(a.z&0xffff0000u)
         + __uint_as_float(u.w<<16)*__uint_as_float(a.w<<16)
         + __uint_as_float(u.w&0xffff0000u)*__uint_as_float(a.w&0xffff0000u);
  }
  float l = (acc >= 0.f) ? acc : 0.2f*acc;
  l = fminf(fmaxf(l, -60.f), 60.f);
  EL[t] = __expf(l);
}

// ---------------- conv aggregation: one wave per dst node, SINGLE PASS ----------------
// acc[c] = sum_e EL[src_e,h]*M[src_e,h,c];  dnl = sum_e EL[src_e,h];  out = acc/dnl.
// Every lane walks every edge, so each lane carries its own head's denominator.
template<int C>
__global__ __launch_bounds__(256) void conv_agg(const int* __restrict__ off,
    const int* __restrict__ csr_src, const float* __restrict__ EL,
    const bf16* __restrict__ Mmsg, const bf16* __restrict__ Hself,
    bf16* __restrict__ Hout)
{
  constexpr int R = 4*C;
  __shared__ float red[4][R];
  const int wave = threadIdx.x >> 6, lane = threadIdx.x & 63;
  const int n = blockIdx.x*4 + wave;
  const int e0 = off[n], e1 = off[n+1];

  const bool active = (8*lane) < R;
  const int hidx = (8*lane) / C;     // head of my 8-channel chunk (C%8==0)
  float acc[8] = {0,0,0,0,0,0,0,0};
  float dnl = 0.f;

  #pragma unroll 2
  for (int e=e0; e<e1; ++e){
    int s = csr_src[e];
    float4 el = *(const float4*)(EL + 4*(size_t)s);
    float wl = (hidx==0)?el.x:(hidx==1)?el.y:(hidx==2)?el.z:el.w;
    dnl += wl;
    if (active){
      const uint4* qp = (const uint4*)(Mmsg + (size_t)s*R) + lane;
      uint4 u = *qp;
      acc[0] += __uint_as_float(u.x<<16)*wl;  acc[1] += __uint_as_float(u.x&0xffff0000u)*wl;
      acc[2] += __uint_as_float(u.y<<16)*wl;  acc[3] += __uint_as_float(u.y&0xffff0000u)*wl;
      acc[4] += __uint_as_float(u.z<<16)*wl;  acc[5] += __uint_as_float(u.z&0xffff0000u)*wl;
      acc[6] += __uint_as_float(u.w<<16)*wl;  acc[7] += __uint_as_float(u.w&0xffff0000u)*wl;
    }
  }

  float rd = 1.f/(dnl + 1e-16f);
  if (active){
    #pragma unroll
    for (int j=0;j<8;++j) red[wave][8*lane+j] = acc[j]*rd;
  }
  __syncthreads();

  // epilogue: mean over heads + self (in-place safe: one thread per element)
  for (int c=lane; c<C; c+=64){
    float v = 0.25f*(red[wave][c] + red[wave][C+c] + red[wave][2*C+c] + red[wave][3*C+c]);
    float sv = b2f(Hself[(size_t)n*C + c]);
    Hout[(size_t)n*C + c] = f2b(v + sv);
  }
}

// ---------------- global mean pool ----------------
__global__ __launch_bounds__(256) void pool_kernel(const bf16* __restrict__ H3,
    const int* __restrict__ batch, float* __restrict__ pooled){
  int g = blockIdx.x;
  __shared__ int sb[2];
  if (threadIdx.x < 2){
    int target = g + threadIdx.x;
    int lo=0, hi=NN;
    while (lo<hi){ int mid=(lo+hi)>>1; if (batch[mid]<target) lo=mid+1; else hi=mid; }
    sb[threadIdx.x]=lo;
  }
  __syncthreads();
  int start=sb[0], end=sb[1];
  int c = threadIdx.x & 63, rg = threadIdx.x >> 6;
  float acc=0.f;
  for (int r=start+rg; r<end; r+=4) acc += b2f(H3[(size_t)r*CC3 + c]);
  __shared__ float red[256];
  red[threadIdx.x]=acc; __syncthreads();
  if (threadIdx.x < 64){
    float s = red[c]+red[64+c]+red[128+c]+red[192+c];
    float cnt = (float)(end-start);
    pooled[g*CC3 + c] = s / fmaxf(cnt, 1.0f);
  }
}

// ---------------- classifier + log_softmax (f32 output) ----------------
__global__ __launch_bounds__(64) void fc_kernel(const float* __restrict__ pooled,
    const bf16* __restrict__ Wfc, const bf16* __restrict__ bfc, float* __restrict__ out){
  int g = blockIdx.x, t = threadIdx.x;
  __shared__ float p[CC3];
  __shared__ float lg[NOUT];
  p[t] = pooled[g*CC3 + t];
  __syncthreads();
  if (t < NOUT){
    float a = b2f(bfc[t]);
    for (int c=0;c<CC3;++c) a += p[c]*b2f(Wfc[c*NOUT + t]);
    lg[t] = a;
  }
  __syncthreads();
  if (t < NOUT){
    float m = -INFINITY;
    #pragma unroll
    for (int i=0;i<NOUT;++i) m = fmaxf(m, lg[i]);
    float s = 0.f;
    #pragma unroll
    for (int i=0;i<NOUT;++i) s += __expf(lg[i]-m);
    out[g*NOUT + t] = lg[t] - m - __logf(s);
  }
}

extern "C" void kernel_launch(void* const* d_in, const int* in_sizes, int n_in,
                              void* d_out, int out_size, void* d_ws, size_t ws_size,
                              hipStream_t stream) {
  const float* xf    = (const float*)d_in[0];
  const int*   ei    = (const int*)d_in[1];
  const int*   batch = (const int*)d_in[2];
  const float* pWm1  = (const float*)d_in[3];
  const float* pbm1  = (const float*)d_in[4];
  const float* patt1 = (const float*)d_in[5];
  const float* pWs1  = (const float*)d_in[6];
  const float* pbs1  = (const float*)d_in[7];
  const float* pWm2  = (const float*)d_in[8];
  const float* pbm2  = (const float*)d_in[9];
  const float* patt2 = (const float*)d_in[10];
  const float* pWm3  = (const float*)d_in[11];
  const float* pbm3  = (const float*)d_in[12];
  const float* patt3 = (const float*)d_in[13];
  const float* pWs3  = (const float*)d_in[14];
  const float* pbs3  = (const float*)d_in[15];
  const float* pWfc  = (const float*)d_in[16];
  const float* pbfc  = (const float*)d_in[17];

  // ---- workspace layout, lifetime-aliased ----
  char* p = (char*)d_ws;
  auto alloc = [&](size_t bytes)->char*{ char* q = p; p += (bytes + 255) & ~(size_t)255; return q; };
  int*   deg     = (int*)  alloc(NN*sizeof(int));
  int*   off     = (int*)  alloc((NN+1)*sizeof(int));
  int*   cursor  = (int*)  alloc(NN*sizeof(int));
  int*   csr_src = (int*)  alloc(NE*sizeof(int));
  int*   partials= (int*)  alloc(NPART*sizeof(int));
  float* EL      = (float*)alloc((size_t)NN*4*sizeof(float));
  bf16*  Mb      = (bf16*) alloc((size_t)NN*384*sizeof(bf16));   // 38.4 MB, reused per layer
  bf16*  H1b     = (bf16*) alloc((size_t)NN*96*sizeof(bf16));    // 9.6 MB; H3 aliases this
  bf16*  H2b     = (bf16*) alloc((size_t)NN*96*sizeof(bf16));    // 9.6 MB
  float* pooled  = (float*)alloc((size_t)NG*CC3*sizeof(float));
  bf16*  xb      = (bf16*) alloc((size_t)NN*FIN*sizeof(bf16));   // 6.4 MB
  // transposed bf16 weights [Nc,K]
  bf16*  Wm1T = (bf16*)alloc(384*FIN*sizeof(bf16));
  bf16*  Ws1T = (bf16*)alloc(96*FIN*sizeof(bf16));
  bf16*  Wm2T = (bf16*)alloc(384*HID*sizeof(bf16));
  bf16*  Wm3T = (bf16*)alloc(256*HID*sizeof(bf16));
  bf16*  Ws3T = (bf16*)alloc(64*HID*sizeof(bf16));
  // small bf16 casts
  bf16*  bm1 = (bf16*)alloc(384*sizeof(bf16));
  bf16*  att1= (bf16*)alloc(384*sizeof(bf16));
  bf16*  bs1 = (bf16*)alloc(96*sizeof(bf16));
  bf16*  bm2 = (bf16*)alloc(384*sizeof(bf16));
  bf16*  att2= (bf16*)alloc(384*sizeof(bf16));
  bf16*  bm3 = (bf16*)alloc(256*sizeof(bf16));
  bf16*  att3= (bf16*)alloc(256*sizeof(bf16));
  bf16*  bs3 = (bf16*)alloc(64*sizeof(bf16));
  bf16*  Wfc = (bf16*)alloc(CC3*NOUT*sizeof(bf16));
  bf16*  bfc = (bf16*)alloc(NOUT*sizeof(bf16));
  bf16*  H3b = H1b;   // H1 dead after layer-2 aggregation (stream-ordered)

  // ---- prologue: casts + weight transposes ----
  CastJobs cj;
  int ji = 0;
  auto addj = [&](const float* s, bf16* d, int n){ cj.src[ji]=s; cj.dst[ji]=d; cj.n[ji]=n; ++ji; };
  addj(xf,   xb,   NN*FIN);
  addj(pbm1, bm1, 384); addj(patt1, att1, 384); addj(pbs1, bs1, 96);
  addj(pbm2, bm2, 384); addj(patt2, att2, 384);
  addj(pbm3, bm3, 256); addj(patt3, att3, 256); addj(pbs3, bs3, 64);
  addj(pWfc, Wfc,  CC3*NOUT); addj(pbfc, bfc, NOUT);
  cast_kernel<<<2048, 256, 0, stream>>>(cj);

  TransJobs tj;
  tj.W[0]=pWm1; tj.WT[0]=Wm1T; tj.K[0]=FIN; tj.Nc[0]=384;
  tj.W[1]=pWs1; tj.WT[1]=Ws1T; tj.K[1]=FIN; tj.Nc[1]=96;
  tj.W[2]=pWm2; tj.WT[2]=Wm2T; tj.K[2]=HID; tj.Nc[2]=384;
  tj.W[3]=pWm3; tj.WT[3]=Wm3T; tj.K[3]=HID; tj.Nc[3]=256;
  tj.W[4]=pWs3; tj.WT[4]=Ws3T; tj.K[4]=HID; tj.Nc[4]=64;
  trans_kernel<<<256, 256, 0, stream>>>(tj);

  // ---- CSR build (hierarchical scan; reused by all 3 layers) ----
  hipMemsetAsync(deg, 0, NN*sizeof(int), stream);
  deg_kernel<<<(NE+255)/256, 256, 0, stream>>>(ei, deg);
  scan_part_kernel<<<NPART, 256, 0, stream>>>(deg, partials);
  scan_top_kernel<<<1, 256, 0, stream>>>(partials, off);
  scan_final_kernel<<<NPART, 256, 0, stream>>>(deg, partials, off, cursor);
  scatter_kernel<<<(NE+255)/256, 256, 0, stream>>>(ei, cursor, csr_src);

  const int MB128 = (NN + 127)/128;       // 391 row blocks (MFMA)
  const int LB = (NN*4 + 255)/256;        // expl blocks
  const int AB = NN/4;                    // 12500 agg blocks (4 waves each)

  // ---- layer 1: FIN=64 -> HID=96 ----
  gemm_mfma<64><<<dim3(MB128,2), 256, 0, stream>>>(xb, Ws1T, bs1, H1b, NN, 96);  // self pre-fill
  gemm_mfma<64><<<dim3(MB128,6), 256, 0, stream>>>(xb, Wm1T, bm1, Mb, NN, 384);
  expl_kernel<<<LB, 256, 0, stream>>>(Mb, att1, EL, 96);
  conv_agg<96><<<AB, 256, 0, stream>>>(off, csr_src, EL, Mb, H1b, H1b);          // in-place += agg

  // ---- layer 2: HID -> HID (identity self) ----
  gemm_mfma<96><<<dim3(MB128,6), 256, 0, stream>>>(H1b, Wm2T, bm2, Mb, NN, 384);
  expl_kernel<<<LB, 256, 0, stream>>>(Mb, att2, EL, 96);
  conv_agg<96><<<AB, 256, 0, stream>>>(off, csr_src, EL, Mb, H1b, H2b);

  // ---- layer 3: HID -> CC3=64 ----
  gemm_mfma<96><<<dim3(MB128,4), 256, 0, stream>>>(H2b, Wm3T, bm3, Mb, NN, 256);
  gemm_mfma<96><<<dim3(MB128,1), 256, 0, stream>>>(H2b, Ws3T, bs3, H3b, NN, 64); // self pre-fill
  expl_kernel<<<LB, 256, 0, stream>>>(Mb, att3, EL, 64);
  conv_agg<64><<<AB, 256, 0, stream>>>(off, csr_src, EL, Mb, H3b, H3b);          // in-place += agg

  // ---- pool + classifier ----
  pool_kernel<<<NG, 256, 0, stream>>>(H3b, batch, pooled);
  fc_kernel<<<NG, 64, 0, stream>>>(pooled, Wfc, bfc, (float*)d_out);
}

// Round 8
// 503.925 us; speedup vs baseline: 2.8773x; 1.1804x over previous
//
#include <hip/hip_runtime.h>
#include <hip/hip_bf16.h>
#include <stdint.h>

using bf16 = __hip_bfloat16;
typedef __attribute__((ext_vector_type(8))) short bf16x8;
typedef __attribute__((ext_vector_type(4))) float f32x4;

#define NN 50000
#define NE 400000
#define NG 64
#define NHEADS 4
#define FIN 64
#define HID 96
#define CC3 64
#define NOUT 10

#define SCAN_BLOCK 256
#define NPART ((NN + SCAN_BLOCK - 1) / SCAN_BLOCK)   // 196 (<=256)

__device__ __forceinline__ float b2f(bf16 h){ return __bfloat162float(h); }
__device__ __forceinline__ bf16 f2b(float f){ return __float2bfloat16(f); }

// ---------------- prologue: cast f32 inputs -> bf16 copies ----------------
#define NJOBS 11
struct CastJobs {
  const float* src[NJOBS];
  bf16*        dst[NJOBS];
  int          n[NJOBS];
};
__global__ __launch_bounds__(256) void cast_kernel(CastJobs j){
  for (int t=0; t<NJOBS; ++t){
    int n = j.n[t];
    const float* s = j.src[t];
    bf16* d = j.dst[t];
    for (int i = blockIdx.x*256 + threadIdx.x; i < n; i += gridDim.x*256)
      d[i] = f2b(s[i]);
  }
}

// ---------------- prologue: transpose weights f32[K,Nc] -> bf16 WT[Nc,K] ----------------
#define NTJOBS 5
struct TransJobs {
  const float* W[NTJOBS];
  bf16*        WT[NTJOBS];
  int          K[NTJOBS];
  int          Nc[NTJOBS];
};
__global__ __launch_bounds__(256) void trans_kernel(TransJobs j){
  for (int t=0; t<NTJOBS; ++t){
    int K = j.K[t], Nc = j.Nc[t], total = K*Nc;
    for (int i = blockIdx.x*256 + threadIdx.x; i < total; i += gridDim.x*256){
      int k = i / Nc, n = i % Nc;
      j.WT[t][(size_t)n*K + k] = f2b(j.W[t][i]);
    }
  }
}

// ---------------- CSR build ----------------
__global__ void deg_kernel(const int* __restrict__ ei, int* __restrict__ deg){
  int e = blockIdx.x*256 + threadIdx.x;
  if (e < NE) atomicAdd(&deg[ei[NE + e]], 1);
}

__global__ __launch_bounds__(256) void scan_part_kernel(const int* __restrict__ deg,
                                                        int* __restrict__ partials){
  int i = blockIdx.x*SCAN_BLOCK + threadIdx.x;
  int v = (i < NN) ? deg[i] : 0;
  __shared__ int ws[4];
  int lane = threadIdx.x & 63, w = threadIdx.x >> 6;
  int s = v;
  #pragma unroll
  for (int m=1;m<64;m<<=1) s += __shfl_xor(s,m);
  if (lane==0) ws[w]=s;
  __syncthreads();
  if (threadIdx.x==0) partials[blockIdx.x] = ws[0]+ws[1]+ws[2]+ws[3];
}

__global__ __launch_bounds__(256) void scan_top_kernel(int* __restrict__ partials,
                                                       int* __restrict__ off){
  __shared__ int buf[256];
  int t = threadIdx.x;
  int v = (t < NPART) ? partials[t] : 0;
  buf[t] = v; __syncthreads();
  for (int s=1;s<256;s<<=1){
    int x = (t>=s) ? buf[t-s] : 0;
    __syncthreads();
    buf[t] += x;
    __syncthreads();
  }
  if (t < NPART) partials[t] = buf[t] - v;   // exclusive
  if (t == 0) off[NN] = buf[255];
}

__global__ __launch_bounds__(256) void scan_final_kernel(const int* __restrict__ deg,
    const int* __restrict__ partials, int* __restrict__ off, int* __restrict__ cursor){
  __shared__ int buf[256];
  int i = blockIdx.x*SCAN_BLOCK + threadIdx.x;
  int t = threadIdx.x;
  int v = (i<NN) ? deg[i] : 0;
  buf[t] = v; __syncthreads();
  for (int s=1;s<256;s<<=1){
    int x = (t>=s) ? buf[t-s] : 0;
    __syncthreads();
    buf[t] += x;
    __syncthreads();
  }
  int ex = partials[blockIdx.x] + buf[t] - v;
  if (i<NN){ off[i]=ex; cursor[i]=ex; }
}

__global__ void scatter_kernel(const int* __restrict__ ei, int* __restrict__ cursor,
                               int* __restrict__ csr_src){
  int e = blockIdx.x*256 + threadIdx.x;
  if (e < NE){
    int d = ei[NE + e];
    int slot = atomicAdd(&cursor[d], 1);
    csr_src[slot] = ei[e];
  }
}

// ---------------- MFMA GEMM: out[M,Nc](bf16) = A[M,K](bf16) @ W + bias ----------------
// W supplied TRANSPOSED: WT[Nc,K]. A-frag & B-frag are contiguous 16B/lane loads.
// D layout (m89-verified): col=lane&15, row=(lane>>4)*4+reg.
// block = 4 waves, tile 128 rows x 64 cols; wave tile 32x64.
template<int K>
__global__ __launch_bounds__(256) void gemm_mfma(const bf16* __restrict__ A,
    const bf16* __restrict__ WT, const bf16* __restrict__ bias,
    bf16* __restrict__ out, int Mrows, int Nc)
{
  const int wave = threadIdx.x >> 6, lane = threadIdx.x & 63;
  const int r0 = blockIdx.x*128 + wave*32;
  const int c0 = blockIdx.y*64;
  const int lm = lane & 15, q = lane >> 4;

  f32x4 acc[2][4] = {};
  const bf16x8 zfrag = {0,0,0,0,0,0,0,0};

  #pragma unroll
  for (int kt=0; kt<K/32; ++kt){
    const int kk = kt*32 + q*8;
    bf16x8 afrag[2];
    #pragma unroll
    for (int i=0;i<2;++i){
      int row = r0 + i*16 + lm;
      afrag[i] = (row < Mrows) ? *(const bf16x8*)(A + (size_t)row*K + kk) : zfrag;
    }
    #pragma unroll
    for (int t=0;t<4;++t){
      int col = c0 + t*16 + lm;
      bf16x8 bfrag = (col < Nc) ? *(const bf16x8*)(WT + (size_t)col*K + kk) : zfrag;
      #pragma unroll
      for (int i=0;i<2;++i)
        acc[i][t] = __builtin_amdgcn_mfma_f32_16x16x32_bf16(afrag[i], bfrag, acc[i][t], 0,0,0);
    }
  }

  #pragma unroll
  for (int t=0;t<4;++t){
    int col = c0 + t*16 + lm;
    if (col >= Nc) continue;
    float bv = b2f(bias[col]);
    #pragma unroll
    for (int i=0;i<2;++i){
      #pragma unroll
      for (int r=0;r<4;++r){
        int row = r0 + i*16 + q*4 + r;
        if (row < Mrows) out[(size_t)row*Nc + col] = f2b(acc[i][t][r] + bv);
      }
    }
  }
}

// ---------------- per-node attention exp-logits ----------------
// EL[n,h] = exp(clamp(leaky_relu(sum_c M[n,h*C+c]*att[h,c], 0.2), +-60))
__global__ void expl_kernel(const bf16* __restrict__ M, const bf16* __restrict__ att,
                            float* __restrict__ EL, int C){
  int t = blockIdx.x*256 + threadIdx.x;
  if (t >= NN*NHEADS) return;
  int n = t >> 2, h = t & 3;
  const uint4* row = (const uint4*)(M + (size_t)n*NHEADS*C + h*C);
  const uint4* av  = (const uint4*)(att + h*C);
  float acc = 0.f;
  for (int c8=0; c8<C/8; ++c8){
    uint4 u = row[c8], a = av[c8];
    acc += __uint_as_float(u.x<<16)*__uint_as_float(a.x<<16)
         + __uint_as_float(u.x&0xffff0000u)*__uint_as_float(a.x&0xffff0000u)
         + __uint_as_float(u.y<<16)*__uint_as_float(a.y<<16)
         + __uint_as_float(u.y&0xffff0000u)*__uint_as_float(a.y&0xffff0000u)
         + __uint_as_float(u.z<<16)*__uint_as_float(a.z<<16)
         + __uint_as_float(u.z&0xffff0000u)*__uint_as_float(a.z&0xffff0000u)
         + __uint_as_float(u.w<<16)*__uint_as_float(a.w<<16)
         + __uint_as_float(u.w&0xffff0000u)*__uint_as_float(a.w&0xffff0000u);
  }
  float l = (acc >= 0.f) ? acc : 0.2f*acc;
  l = fminf(fmaxf(l, -60.f), 60.f);
  EL[t] = __expf(l);
}

// ---------------- conv aggregation: one wave per dst node, SINGLE PASS ----------------
// Wave-staged: lanes cooperatively preload up to 64 edge indices + EL quads
// (one coalesced load + one parallel gather), then the per-edge loop gets s and
// the head weights via __shfl(reg, j) (uniform j -> v_readlane, SGPR broadcast).
// M-row gathers across edges are then independent -> deep MLP.
template<int C>
__global__ __launch_bounds__(256) void conv_agg(const int* __restrict__ off,
    const int* __restrict__ csr_src, const float* __restrict__ EL,
    const bf16* __restrict__ Mmsg, const bf16* __restrict__ Hself,
    bf16* __restrict__ Hout)
{
  constexpr int R = 4*C;
  __shared__ float red[4][R];
  const int wave = threadIdx.x >> 6, lane = threadIdx.x & 63;
  const int n = blockIdx.x*4 + wave;
  const int e0 = off[n], e1 = off[n+1];

  const bool active = (8*lane) < R;
  const int hidx = (8*lane) / C;     // head of my 8-channel chunk (C%8==0)
  float acc[8] = {0,0,0,0,0,0,0,0};
  float dnl = 0.f;

  for (int base=e0; base<e1; base+=64){
    const int cnt = min(64, e1-base);
    int sreg = 0;
    float4 el = make_float4(0.f,0.f,0.f,0.f);
    if (lane < cnt){
      sreg = csr_src[base+lane];                       // coalesced
      el = *(const float4*)(EL + 4*(size_t)sreg);      // parallel gather
    }
    #pragma unroll 4
    for (int j=0; j<cnt; ++j){
      int s = __shfl(sreg, j);                         // v_readlane -> SGPR
      float ex=__shfl(el.x,j), ey=__shfl(el.y,j), ez=__shfl(el.z,j), ew=__shfl(el.w,j);
      float wl = (hidx==0)?ex:(hidx==1)?ey:(hidx==2)?ez:ew;
      dnl += wl;
      if (active){
        const uint4* qp = (const uint4*)(Mmsg + (size_t)s*R) + lane;
        uint4 u = *qp;
        acc[0] += __uint_as_float(u.x<<16)*wl;  acc[1] += __uint_as_float(u.x&0xffff0000u)*wl;
        acc[2] += __uint_as_float(u.y<<16)*wl;  acc[3] += __uint_as_float(u.y&0xffff0000u)*wl;
        acc[4] += __uint_as_float(u.z<<16)*wl;  acc[5] += __uint_as_float(u.z&0xffff0000u)*wl;
        acc[6] += __uint_as_float(u.w<<16)*wl;  acc[7] += __uint_as_float(u.w&0xffff0000u)*wl;
      }
    }
  }

  float rd = 1.f/(dnl + 1e-16f);
  if (active){
    #pragma unroll
    for (int j=0;j<8;++j) red[wave][8*lane+j] = acc[j]*rd;
  }
  __syncthreads();

  // epilogue: mean over heads + self (in-place safe: one thread per element)
  for (int c=lane; c<C; c+=64){
    float v = 0.25f*(red[wave][c] + red[wave][C+c] + red[wave][2*C+c] + red[wave][3*C+c]);
    float sv = b2f(Hself[(size_t)n*C + c]);
    Hout[(size_t)n*C + c] = f2b(v + sv);
  }
}

// ---------------- global mean pool ----------------
__global__ __launch_bounds__(256) void pool_kernel(const bf16* __restrict__ H3,
    const int* __restrict__ batch, float* __restrict__ pooled){
  int g = blockIdx.x;
  __shared__ int sb[2];
  if (threadIdx.x < 2){
    int target = g + threadIdx.x;
    int lo=0, hi=NN;
    while (lo<hi){ int mid=(lo+hi)>>1; if (batch[mid]<target) lo=mid+1; else hi=mid; }
    sb[threadIdx.x]=lo;
  }
  __syncthreads();
  int start=sb[0], end=sb[1];
  int c = threadIdx.x & 63, rg = threadIdx.x >> 6;
  float acc=0.f;
  for (int r=start+rg; r<end; r+=4) acc += b2f(H3[(size_t)r*CC3 + c]);
  __shared__ float red[256];
  red[threadIdx.x]=acc; __syncthreads();
  if (threadIdx.x < 64){
    float s = red[c]+red[64+c]+red[128+c]+red[192+c];
    float cnt = (float)(end-start);
    pooled[g*CC3 + c] = s / fmaxf(cnt, 1.0f);
  }
}

// ---------------- classifier + log_softmax (f32 output) ----------------
__global__ __launch_bounds__(64) void fc_kernel(const float* __restrict__ pooled,
    const bf16* __restrict__ Wfc, const bf16* __restrict__ bfc, float* __restrict__ out){
  int g = blockIdx.x, t = threadIdx.x;
  __shared__ float p[CC3];
  __shared__ float lg[NOUT];
  p[t] = pooled[g*CC3 + t];
  __syncthreads();
  if (t < NOUT){
    float a = b2f(bfc[t]);
    for (int c=0;c<CC3;++c) a += p[c]*b2f(Wfc[c*NOUT + t]);
    lg[t] = a;
  }
  __syncthreads();
  if (t < NOUT){
    float m = -INFINITY;
    #pragma unroll
    for (int i=0;i<NOUT;++i) m = fmaxf(m, lg[i]);
    float s = 0.f;
    #pragma unroll
    for (int i=0;i<NOUT;++i) s += __expf(lg[i]-m);
    out[g*NOUT + t] = lg[t] - m - __logf(s);
  }
}

extern "C" void kernel_launch(void* const* d_in, const int* in_sizes, int n_in,
                              void* d_out, int out_size, void* d_ws, size_t ws_size,
                              hipStream_t stream) {
  const float* xf    = (const float*)d_in[0];
  const int*   ei    = (const int*)d_in[1];
  const int*   batch = (const int*)d_in[2];
  const float* pWm1  = (const float*)d_in[3];
  const float* pbm1  = (const float*)d_in[4];
  const float* patt1 = (const float*)d_in[5];
  const float* pWs1  = (const float*)d_in[6];
  const float* pbs1  = (const float*)d_in[7];
  const float* pWm2  = (const float*)d_in[8];
  const float* pbm2  = (const float*)d_in[9];
  const float* patt2 = (const float*)d_in[10];
  const float* pWm3  = (const float*)d_in[11];
  const float* pbm3  = (const float*)d_in[12];
  const float* patt3 = (const float*)d_in[13];
  const float* pWs3  = (const float*)d_in[14];
  const float* pbs3  = (const float*)d_in[15];
  const float* pWfc  = (const float*)d_in[16];
  const float* pbfc  = (const float*)d_in[17];

  // ---- workspace layout, lifetime-aliased ----
  char* p = (char*)d_ws;
  auto alloc = [&](size_t bytes)->char*{ char* q = p; p += (bytes + 255) & ~(size_t)255; return q; };
  int*   deg     = (int*)  alloc(NN*sizeof(int));
  int*   off     = (int*)  alloc((NN+1)*sizeof(int));
  int*   cursor  = (int*)  alloc(NN*sizeof(int));
  int*   csr_src = (int*)  alloc(NE*sizeof(int));
  int*   partials= (int*)  alloc(NPART*sizeof(int));
  float* EL      = (float*)alloc((size_t)NN*4*sizeof(float));
  bf16*  Mb      = (bf16*) alloc((size_t)NN*384*sizeof(bf16));   // 38.4 MB, reused per layer
  bf16*  H1b     = (bf16*) alloc((size_t)NN*96*sizeof(bf16));    // 9.6 MB; H3 aliases this
  bf16*  H2b     = (bf16*) alloc((size_t)NN*96*sizeof(bf16));    // 9.6 MB
  float* pooled  = (float*)alloc((size_t)NG*CC3*sizeof(float));
  bf16*  xb      = (bf16*) alloc((size_t)NN*FIN*sizeof(bf16));   // 6.4 MB
  // transposed bf16 weights [Nc,K]
  bf16*  Wm1T = (bf16*)alloc(384*FIN*sizeof(bf16));
  bf16*  Ws1T = (bf16*)alloc(96*FIN*sizeof(bf16));
  bf16*  Wm2T = (bf16*)alloc(384*HID*sizeof(bf16));
  bf16*  Wm3T = (bf16*)alloc(256*HID*sizeof(bf16));
  bf16*  Ws3T = (bf16*)alloc(64*HID*sizeof(bf16));
  // small bf16 casts
  bf16*  bm1 = (bf16*)alloc(384*sizeof(bf16));
  bf16*  att1= (bf16*)alloc(384*sizeof(bf16));
  bf16*  bs1 = (bf16*)alloc(96*sizeof(bf16));
  bf16*  bm2 = (bf16*)alloc(384*sizeof(bf16));
  bf16*  att2= (bf16*)alloc(384*sizeof(bf16));
  bf16*  bm3 = (bf16*)alloc(256*sizeof(bf16));
  bf16*  att3= (bf16*)alloc(256*sizeof(bf16));
  bf16*  bs3 = (bf16*)alloc(64*sizeof(bf16));
  bf16*  Wfc = (bf16*)alloc(CC3*NOUT*sizeof(bf16));
  bf16*  bfc = (bf16*)alloc(NOUT*sizeof(bf16));
  bf16*  H3b = H1b;   // H1 dead after layer-2 aggregation (stream-ordered)

  // ---- prologue: casts + weight transposes ----
  CastJobs cj;
  int ji = 0;
  auto addj = [&](const float* s, bf16* d, int n){ cj.src[ji]=s; cj.dst[ji]=d; cj.n[ji]=n; ++ji; };
  addj(xf,   xb,   NN*FIN);
  addj(pbm1, bm1, 384); addj(patt1, att1, 384); addj(pbs1, bs1, 96);
  addj(pbm2, bm2, 384); addj(patt2, att2, 384);
  addj(pbm3, bm3, 256); addj(patt3, att3, 256); addj(pbs3, bs3, 64);
  addj(pWfc, Wfc,  CC3*NOUT); addj(pbfc, bfc, NOUT);
  cast_kernel<<<2048, 256, 0, stream>>>(cj);

  TransJobs tj;
  tj.W[0]=pWm1; tj.WT[0]=Wm1T; tj.K[0]=FIN; tj.Nc[0]=384;
  tj.W[1]=pWs1; tj.WT[1]=Ws1T; tj.K[1]=FIN; tj.Nc[1]=96;
  tj.W[2]=pWm2; tj.WT[2]=Wm2T; tj.K[2]=HID; tj.Nc[2]=384;
  tj.W[3]=pWm3; tj.WT[3]=Wm3T; tj.K[3]=HID; tj.Nc[3]=256;
  tj.W[4]=pWs3; tj.WT[4]=Ws3T; tj.K[4]=HID; tj.Nc[4]=64;
  trans_kernel<<<256, 256, 0, stream>>>(tj);

  // ---- CSR build (hierarchical scan; reused by all 3 layers) ----
  hipMemsetAsync(deg, 0, NN*sizeof(int), stream);
  deg_kernel<<<(NE+255)/256, 256, 0, stream>>>(ei, deg);
  scan_part_kernel<<<NPART, 256, 0, stream>>>(deg, partials);
  scan_top_kernel<<<1, 256, 0, stream>>>(partials, off);
  scan_final_kernel<<<NPART, 256, 0, stream>>>(deg, partials, off, cursor);
  scatter_kernel<<<(NE+255)/256, 256, 0, stream>>>(ei, cursor, csr_src);

  const int MB128 = (NN + 127)/128;       // 391 row blocks (MFMA)
  const int LB = (NN*4 + 255)/256;        // expl blocks
  const int AB = NN/4;                    // 12500 agg blocks (4 waves each)

  // ---- layer 1: FIN=64 -> HID=96 ----
  gemm_mfma<64><<<dim3(MB128,2), 256, 0, stream>>>(xb, Ws1T, bs1, H1b, NN, 96);  // self pre-fill
  gemm_mfma<64><<<dim3(MB128,6), 256, 0, stream>>>(xb, Wm1T, bm1, Mb, NN, 384);
  expl_kernel<<<LB, 256, 0, stream>>>(Mb, att1, EL, 96);
  conv_agg<96><<<AB, 256, 0, stream>>>(off, csr_src, EL, Mb, H1b, H1b);          // in-place += agg

  // ---- layer 2: HID -> HID (identity self) ----
  gemm_mfma<96><<<dim3(MB128,6), 256, 0, stream>>>(H1b, Wm2T, bm2, Mb, NN, 384);
  expl_kernel<<<LB, 256, 0, stream>>>(Mb, att2, EL, 96);
  conv_agg<96><<<AB, 256, 0, stream>>>(off, csr_src, EL, Mb, H1b, H2b);

  // ---- layer 3: HID -> CC3=64 ----
  gemm_mfma<96><<<dim3(MB128,4), 256, 0, stream>>>(H2b, Wm3T, bm3, Mb, NN, 256);
  gemm_mfma<96><<<dim3(MB128,1), 256, 0, stream>>>(H2b, Ws3T, bs3, H3b, NN, 64); // self pre-fill
  expl_kernel<<<LB, 256, 0, stream>>>(Mb, att3, EL, 64);
  conv_agg<64><<<AB, 256, 0, stream>>>(off, csr_src, EL, Mb, H3b, H3b);          // in-place += agg

  // ---- pool + classifier ----
  pool_kernel<<<NG, 256, 0, stream>>>(H3b, batch, pooled);
  fc_kernel<<<NG, 64, 0, stream>>>(pooled, Wfc, bfc, (float*)d_out);
}

// Round 9
// 456.663 us; speedup vs baseline: 3.1751x; 1.1035x over previous
//
#include <hip/hip_runtime.h>
#include <hip/hip_bf16.h>
#include <stdint.h>

using bf16 = __hip_bfloat16;
typedef __attribute__((ext_vector_type(8))) short bf16x8;
typedef __attribute__((ext_vector_type(4))) float f32x4;

#define NN 50000
#define NE 400000
#define NG 64
#define NHEADS 4
#define FIN 64
#define HID 96
#define CC3 64
#define NOUT 10

#define SCAN_BLOCK 256
#define NPART ((NN + SCAN_BLOCK - 1) / SCAN_BLOCK)   // 196 (<=256)

__device__ __forceinline__ float b2f(bf16 h){ return __bfloat162float(h); }
__device__ __forceinline__ bf16 f2b(float f){ return __float2bfloat16(f); }

// ---------------- prologue: cast f32 inputs -> bf16 copies ----------------
#define NJOBS 11
struct CastJobs {
  const float* src[NJOBS];
  bf16*        dst[NJOBS];
  int          n[NJOBS];
};
__global__ __launch_bounds__(256) void cast_kernel(CastJobs j){
  for (int t=0; t<NJOBS; ++t){
    int n = j.n[t];
    const float* s = j.src[t];
    bf16* d = j.dst[t];
    for (int i = blockIdx.x*256 + threadIdx.x; i < n; i += gridDim.x*256)
      d[i] = f2b(s[i]);
  }
}

// ---------------- prologue: transpose weights f32[K,Nc] -> bf16 WT[Nc,K] ----------------
#define NTJOBS 5
struct TransJobs {
  const float* W[NTJOBS];
  bf16*        WT[NTJOBS];
  int          K[NTJOBS];
  int          Nc[NTJOBS];
};
__global__ __launch_bounds__(256) void trans_kernel(TransJobs j){
  for (int t=0; t<NTJOBS; ++t){
    int K = j.K[t], Nc = j.Nc[t], total = K*Nc;
    for (int i = blockIdx.x*256 + threadIdx.x; i < total; i += gridDim.x*256){
      int k = i / Nc, n = i % Nc;
      j.WT[t][(size_t)n*K + k] = f2b(j.W[t][i]);
    }
  }
}

// ---------------- CSR build ----------------
__global__ void deg_kernel(const int* __restrict__ ei, int* __restrict__ deg){
  int e = blockIdx.x*256 + threadIdx.x;
  if (e < NE) atomicAdd(&deg[ei[NE + e]], 1);
}

__global__ __launch_bounds__(256) void scan_part_kernel(const int* __restrict__ deg,
                                                        int* __restrict__ partials){
  int i = blockIdx.x*SCAN_BLOCK + threadIdx.x;
  int v = (i < NN) ? deg[i] : 0;
  __shared__ int ws[4];
  int lane = threadIdx.x & 63, w = threadIdx.x >> 6;
  int s = v;
  #pragma unroll
  for (int m=1;m<64;m<<=1) s += __shfl_xor(s,m);
  if (lane==0) ws[w]=s;
  __syncthreads();
  if (threadIdx.x==0) partials[blockIdx.x] = ws[0]+ws[1]+ws[2]+ws[3];
}

__global__ __launch_bounds__(256) void scan_top_kernel(int* __restrict__ partials,
                                                       int* __restrict__ off){
  __shared__ int buf[256];
  int t = threadIdx.x;
  int v = (t < NPART) ? partials[t] : 0;
  buf[t] = v; __syncthreads();
  for (int s=1;s<256;s<<=1){
    int x = (t>=s) ? buf[t-s] : 0;
    __syncthreads();
    buf[t] += x;
    __syncthreads();
  }
  if (t < NPART) partials[t] = buf[t] - v;   // exclusive
  if (t == 0) off[NN] = buf[255];
}

__global__ __launch_bounds__(256) void scan_final_kernel(const int* __restrict__ deg,
    const int* __restrict__ partials, int* __restrict__ off, int* __restrict__ cursor){
  __shared__ int buf[256];
  int i = blockIdx.x*SCAN_BLOCK + threadIdx.x;
  int t = threadIdx.x;
  int v = (i<NN) ? deg[i] : 0;
  buf[t] = v; __syncthreads();
  for (int s=1;s<256;s<<=1){
    int x = (t>=s) ? buf[t-s] : 0;
    __syncthreads();
    buf[t] += x;
    __syncthreads();
  }
  int ex = partials[blockIdx.x] + buf[t] - v;
  if (i<NN){ off[i]=ex; cursor[i]=ex; }
}

__global__ void scatter_kernel(const int* __restrict__ ei, int* __restrict__ cursor,
                               int* __restrict__ csr_src){
  int e = blockIdx.x*256 + threadIdx.x;
  if (e < NE){
    int d = ei[NE + e];
    int slot = atomicAdd(&cursor[d], 1);
    csr_src[slot] = ei[e];
  }
}

// ---------------- MFMA GEMM (A-reuse): out[M,Nc](bf16) = A[M,K](bf16) @ W + bias ----
// WT[Nc,K]. A-fragments staged ONCE in registers, then loop over col-tiles.
// grid = (ceil(M/128), ceil(Nc/128)); block = 4 waves; wave tile 32 rows.
// D layout (m89-verified): col=lane&15, row=(lane>>4)*4+reg.
template<int K>
__global__ __launch_bounds__(256) void gemm_mfma(const bf16* __restrict__ A,
    const bf16* __restrict__ WT, const bf16* __restrict__ bias,
    bf16* __restrict__ out, int Mrows, int Nc)
{
  constexpr int KT = K/32;
  const int wave = threadIdx.x >> 6, lane = threadIdx.x & 63;
  const int r0 = blockIdx.x*128 + wave*32;
  const int lm = lane & 15, q = lane >> 4;
  const bf16x8 zfrag = {0,0,0,0,0,0,0,0};

  bf16x8 afrag[2][KT];
  #pragma unroll
  for (int i=0;i<2;++i){
    int row = r0 + i*16 + lm;
    #pragma unroll
    for (int kt=0; kt<KT; ++kt)
      afrag[i][kt] = (row < Mrows) ? *(const bf16x8*)(A + (size_t)row*K + kt*32 + q*8) : zfrag;
  }

  const int t0 = blockIdx.y*8, t1 = min(t0+8, Nc/16);
  for (int ct=t0; ct<t1; ++ct){
    const int col = ct*16 + lm;
    f32x4 acc[2] = {};
    #pragma unroll
    for (int kt=0; kt<KT; ++kt){
      bf16x8 bfrag = *(const bf16x8*)(WT + (size_t)col*K + kt*32 + q*8);
      #pragma unroll
      for (int i=0;i<2;++i)
        acc[i] = __builtin_amdgcn_mfma_f32_16x16x32_bf16(afrag[i][kt], bfrag, acc[i], 0,0,0);
    }
    float bv = b2f(bias[col]);
    #pragma unroll
    for (int i=0;i<2;++i){
      #pragma unroll
      for (int r=0;r<4;++r){
        int row = r0 + i*16 + q*4 + r;
        if (row < Mrows) out[(size_t)row*Nc + col] = f2b(acc[i][r] + bv);
      }
    }
  }
}

// ---------------- per-node attention exp-logits ----------------
// EL[n,h] = exp(clamp(leaky_relu(sum_c M[n,h*C+c]*att[h,c], 0.2), +-60))
__global__ void expl_kernel(const bf16* __restrict__ M, const bf16* __restrict__ att,
                            float* __restrict__ EL, int C){
  int t = blockIdx.x*256 + threadIdx.x;
  if (t >= NN*NHEADS) return;
  int n = t >> 2, h = t & 3;
  const uint4* row = (const uint4*)(M + (size_t)n*NHEADS*C + h*C);
  const uint4* av  = (const uint4*)(att + h*C);
  float acc = 0.f;
  for (int c8=0; c8<C/8; ++c8){
    uint4 u = row[c8], a = av[c8];
    acc += __uint_as_float(u.x<<16)*__uint_as_float(a.x<<16)
         + __uint_as_float(u.x&0xffff0000u)*__uint_as_float(a.x&0xffff0000u)
         + __uint_as_float(u.y<<16)*__uint_as_float(a.y<<16)
         + __uint_as_float(u.y&0xffff0000u)*__uint_as_float(a.y&0xffff0000u)
         + __uint_as_float(u.z<<16)*__uint_as_float(a.z<<16)
         + __uint_as_float(u.z&0xffff0000u)*__uint_as_float(a.z&0xffff0000u)
         + __uint_as_float(u.w<<16)*__uint_as_float(a.w<<16)
         + __uint_as_float(u.w&0xffff0000u)*__uint_as_float(a.w&0xffff0000u);
  }
  float l = (acc >= 0.f) ? acc : 0.2f*acc;
  l = fminf(fmaxf(l, -60.f), 60.f);
  EL[t] = __expf(l);
}

// ---------------- conv aggregation: one wave per dst node, SINGLE PASS ----------------
template<int C>
__global__ __launch_bounds__(256) void conv_agg(const int* __restrict__ off,
    const int* __restrict__ csr_src, const float* __restrict__ EL,
    const bf16* __restrict__ Mmsg, const bf16* __restrict__ Hself,
    bf16* __restrict__ Hout)
{
  constexpr int R = 4*C;
  __shared__ float red[4][R];
  const int wave = threadIdx.x >> 6, lane = threadIdx.x & 63;
  const int n = blockIdx.x*4 + wave;
  const int e0 = off[n], e1 = off[n+1];

  const bool active = (8*lane) < R;
  const int hidx = (8*lane) / C;     // head of my 8-channel chunk (C%8==0)
  float acc[8] = {0,0,0,0,0,0,0,0};
  float dnl = 0.f;

  for (int base=e0; base<e1; base+=64){
    const int cnt = min(64, e1-base);
    int sreg = 0;
    float4 el = make_float4(0.f,0.f,0.f,0.f);
    if (lane < cnt){
      sreg = csr_src[base+lane];                       // coalesced
      el = *(const float4*)(EL + 4*(size_t)sreg);      // parallel gather
    }
    #pragma unroll 4
    for (int j=0; j<cnt; ++j){
      int s = __shfl(sreg, j);                         // v_readlane -> SGPR
      float ex=__shfl(el.x,j), ey=__shfl(el.y,j), ez=__shfl(el.z,j), ew=__shfl(el.w,j);
      float wl = (hidx==0)?ex:(hidx==1)?ey:(hidx==2)?ez:ew;
      dnl += wl;
      if (active){
        const uint4* qp = (const uint4*)(Mmsg + (size_t)s*R) + lane;
        uint4 u = *qp;
        acc[0] += __uint_as_float(u.x<<16)*wl;  acc[1] += __uint_as_float(u.x&0xffff0000u)*wl;
        acc[2] += __uint_as_float(u.y<<16)*wl;  acc[3] += __uint_as_float(u.y&0xffff0000u)*wl;
        acc[4] += __uint_as_float(u.z<<16)*wl;  acc[5] += __uint_as_float(u.z&0xffff0000u)*wl;
        acc[6] += __uint_as_float(u.w<<16)*wl;  acc[7] += __uint_as_float(u.w&0xffff0000u)*wl;
      }
    }
  }

  float rd = 1.f/(dnl + 1e-16f);
  if (active){
    #pragma unroll
    for (int j=0;j<8;++j) red[wave][8*lane+j] = acc[j]*rd;
  }
  __syncthreads();

  // epilogue: mean over heads + self (in-place safe: one thread per element)
  for (int c=lane; c<C; c+=64){
    float v = 0.25f*(red[wave][c] + red[wave][C+c] + red[wave][2*C+c] + red[wave][3*C+c]);
    float sv = b2f(Hself[(size_t)n*C + c]);
    Hout[(size_t)n*C + c] = f2b(v + sv);
  }
}

// ---------------- global mean pool, stage 1: parallel segmented sum ----------------
// One wave per contiguous 64-row slice; batch ids loaded once (coalesced) and
// broadcast via readlane; flush partial sums on graph change (<=2 flushes/wave).
__global__ __launch_bounds__(256) void pool_kernel(const bf16* __restrict__ H3,
    const int* __restrict__ batch, float* __restrict__ psum){
  const int wave = threadIdx.x >> 6, lane = threadIdx.x & 63;
  const int row0 = (blockIdx.x*4 + wave)*64;
  if (row0 >= NN) return;
  const int cnt = min(64, NN - row0);
  int bv = (lane < cnt) ? batch[row0 + lane] : -1;
  int cur = __shfl(bv, 0);
  float acc = 0.f;
  for (int j=0; j<cnt; ++j){
    int g = __shfl(bv, j);
    if (g != cur){ atomicAdd(&psum[cur*CC3 + lane], acc); acc = 0.f; cur = g; }
    acc += b2f(H3[(size_t)(row0 + j)*CC3 + lane]);
  }
  atomicAdd(&psum[cur*CC3 + lane], acc);
}

// ---------------- classifier + log_softmax (f32 output) ----------------
// Divides psum by segment count (binary search on sorted batch).
__global__ __launch_bounds__(64) void fc_kernel(const float* __restrict__ psum,
    const int* __restrict__ batch, const bf16* __restrict__ Wfc,
    const bf16* __restrict__ bfc, float* __restrict__ out){
  int g = blockIdx.x, t = threadIdx.x;
  __shared__ int sb[2];
  if (t < 2){
    int target = g + t;
    int lo=0, hi=NN;
    while (lo<hi){ int mid=(lo+hi)>>1; if (batch[mid]<target) lo=mid+1; else hi=mid; }
    sb[t]=lo;
  }
  __syncthreads();
  float cnt = (float)(sb[1]-sb[0]);
  __shared__ float p[CC3];
  __shared__ float lg[NOUT];
  p[t] = psum[g*CC3 + t] / fmaxf(cnt, 1.0f);
  __syncthreads();
  if (t < NOUT){
    float a = b2f(bfc[t]);
    for (int c=0;c<CC3;++c) a += p[c]*b2f(Wfc[c*NOUT + t]);
    lg[t] = a;
  }
  __syncthreads();
  if (t < NOUT){
    float m = -INFINITY;
    #pragma unroll
    for (int i=0;i<NOUT;++i) m = fmaxf(m, lg[i]);
    float s = 0.f;
    #pragma unroll
    for (int i=0;i<NOUT;++i) s += __expf(lg[i]-m);
    out[g*NOUT + t] = lg[t] - m - __logf(s);
  }
}

extern "C" void kernel_launch(void* const* d_in, const int* in_sizes, int n_in,
                              void* d_out, int out_size, void* d_ws, size_t ws_size,
                              hipStream_t stream) {
  const float* xf    = (const float*)d_in[0];
  const int*   ei    = (const int*)d_in[1];
  const int*   batch = (const int*)d_in[2];
  const float* pWm1  = (const float*)d_in[3];
  const float* pbm1  = (const float*)d_in[4];
  const float* patt1 = (const float*)d_in[5];
  const float* pWs1  = (const float*)d_in[6];
  const float* pbs1  = (const float*)d_in[7];
  const float* pWm2  = (const float*)d_in[8];
  const float* pbm2  = (const float*)d_in[9];
  const float* patt2 = (const float*)d_in[10];
  const float* pWm3  = (const float*)d_in[11];
  const float* pbm3  = (const float*)d_in[12];
  const float* patt3 = (const float*)d_in[13];
  const float* pWs3  = (const float*)d_in[14];
  const float* pbs3  = (const float*)d_in[15];
  const float* pWfc  = (const float*)d_in[16];
  const float* pbfc  = (const float*)d_in[17];

  // ---- workspace layout, lifetime-aliased ----
  char* p = (char*)d_ws;
  auto alloc = [&](size_t bytes)->char*{ char* q = p; p += (bytes + 255) & ~(size_t)255; return q; };
  int*   deg     = (int*)  alloc(NN*sizeof(int));
  int*   off     = (int*)  alloc((NN+1)*sizeof(int));
  int*   cursor  = (int*)  alloc(NN*sizeof(int));
  int*   csr_src = (int*)  alloc(NE*sizeof(int));
  int*   partials= (int*)  alloc(NPART*sizeof(int));
  float* EL      = (float*)alloc((size_t)NN*4*sizeof(float));
  bf16*  Mb      = (bf16*) alloc((size_t)NN*384*sizeof(bf16));   // 38.4 MB, reused per layer
  bf16*  H1b     = (bf16*) alloc((size_t)NN*96*sizeof(bf16));    // 9.6 MB; H3 aliases this
  bf16*  H2b     = (bf16*) alloc((size_t)NN*96*sizeof(bf16));    // 9.6 MB
  float* psum    = (float*)alloc((size_t)NG*CC3*sizeof(float));
  bf16*  xb      = (bf16*) alloc((size_t)NN*FIN*sizeof(bf16));   // 6.4 MB
  // transposed bf16 weights [Nc,K]
  bf16*  Wm1T = (bf16*)alloc(384*FIN*sizeof(bf16));
  bf16*  Ws1T = (bf16*)alloc(96*FIN*sizeof(bf16));
  bf16*  Wm2T = (bf16*)alloc(384*HID*sizeof(bf16));
  bf16*  Wm3T = (bf16*)alloc(256*HID*sizeof(bf16));
  bf16*  Ws3T = (bf16*)alloc(64*HID*sizeof(bf16));
  // small bf16 casts
  bf16*  bm1 = (bf16*)alloc(384*sizeof(bf16));
  bf16*  att1= (bf16*)alloc(384*sizeof(bf16));
  bf16*  bs1 = (bf16*)alloc(96*sizeof(bf16));
  bf16*  bm2 = (bf16*)alloc(384*sizeof(bf16));
  bf16*  att2= (bf16*)alloc(384*sizeof(bf16));
  bf16*  bm3 = (bf16*)alloc(256*sizeof(bf16));
  bf16*  att3= (bf16*)alloc(256*sizeof(bf16));
  bf16*  bs3 = (bf16*)alloc(64*sizeof(bf16));
  bf16*  Wfc = (bf16*)alloc(CC3*NOUT*sizeof(bf16));
  bf16*  bfc = (bf16*)alloc(NOUT*sizeof(bf16));
  bf16*  H3b = H1b;   // H1 dead after layer-2 aggregation (stream-ordered)

  // ---- prologue: casts + weight transposes ----
  CastJobs cj;
  int ji = 0;
  auto addj = [&](const float* s, bf16* d, int n){ cj.src[ji]=s; cj.dst[ji]=d; cj.n[ji]=n; ++ji; };
  addj(xf,   xb,   NN*FIN);
  addj(pbm1, bm1, 384); addj(patt1, att1, 384); addj(pbs1, bs1, 96);
  addj(pbm2, bm2, 384); addj(patt2, att2, 384);
  addj(pbm3, bm3, 256); addj(patt3, att3, 256); addj(pbs3, bs3, 64);
  addj(pWfc, Wfc,  CC3*NOUT); addj(pbfc, bfc, NOUT);
  cast_kernel<<<2048, 256, 0, stream>>>(cj);

  TransJobs tj;
  tj.W[0]=pWm1; tj.WT[0]=Wm1T; tj.K[0]=FIN; tj.Nc[0]=384;
  tj.W[1]=pWs1; tj.WT[1]=Ws1T; tj.K[1]=FIN; tj.Nc[1]=96;
  tj.W[2]=pWm2; tj.WT[2]=Wm2T; tj.K[2]=HID; tj.Nc[2]=384;
  tj.W[3]=pWm3; tj.WT[3]=Wm3T; tj.K[3]=HID; tj.Nc[3]=256;
  tj.W[4]=pWs3; tj.WT[4]=Ws3T; tj.K[4]=HID; tj.Nc[4]=64;
  trans_kernel<<<256, 256, 0, stream>>>(tj);

  // ---- CSR build (hierarchical scan; reused by all 3 layers) ----
  hipMemsetAsync(deg, 0, NN*sizeof(int), stream);
  hipMemsetAsync(psum, 0, NG*CC3*sizeof(float), stream);
  deg_kernel<<<(NE+255)/256, 256, 0, stream>>>(ei, deg);
  scan_part_kernel<<<NPART, 256, 0, stream>>>(deg, partials);
  scan_top_kernel<<<1, 256, 0, stream>>>(partials, off);
  scan_final_kernel<<<NPART, 256, 0, stream>>>(deg, partials, off, cursor);
  scatter_kernel<<<(NE+255)/256, 256, 0, stream>>>(ei, cursor, csr_src);

  const int MB128 = (NN + 127)/128;       // 391 row blocks (MFMA)
  const int LB = (NN*4 + 255)/256;        // expl blocks
  const int AB = NN/4;                    // 12500 agg blocks (4 waves each)
  const int PB = (NN + 255)/256;          // pool blocks

  // ---- layer 1: FIN=64 -> HID=96 ----
  gemm_mfma<64><<<dim3(MB128,1), 256, 0, stream>>>(xb, Ws1T, bs1, H1b, NN, 96);  // self pre-fill
  gemm_mfma<64><<<dim3(MB128,3), 256, 0, stream>>>(xb, Wm1T, bm1, Mb, NN, 384);
  expl_kernel<<<LB, 256, 0, stream>>>(Mb, att1, EL, 96);
  conv_agg<96><<<AB, 256, 0, stream>>>(off, csr_src, EL, Mb, H1b, H1b);          // in-place += agg

  // ---- layer 2: HID -> HID (identity self) ----
  gemm_mfma<96><<<dim3(MB128,3), 256, 0, stream>>>(H1b, Wm2T, bm2, Mb, NN, 384);
  expl_kernel<<<LB, 256, 0, stream>>>(Mb, att2, EL, 96);
  conv_agg<96><<<AB, 256, 0, stream>>>(off, csr_src, EL, Mb, H1b, H2b);

  // ---- layer 3: HID -> CC3=64 ----
  gemm_mfma<96><<<dim3(MB128,2), 256, 0, stream>>>(H2b, Wm3T, bm3, Mb, NN, 256);
  gemm_mfma<96><<<dim3(MB128,1), 256, 0, stream>>>(H2b, Ws3T, bs3, H3b, NN, 64); // self pre-fill
  expl_kernel<<<LB, 256, 0, stream>>>(Mb, att3, EL, 64);
  conv_agg<64><<<AB, 256, 0, stream>>>(off, csr_src, EL, Mb, H3b, H3b);          // in-place += agg

  // ---- pool (2-stage) + classifier ----
  pool_kernel<<<PB, 256, 0, stream>>>(H3b, batch, psum);
  fc_kernel<<<NG, 64, 0, stream>>>(psum, batch, Wfc, bfc, (float*)d_out);
}

// Round 10
// 445.406 us; speedup vs baseline: 3.2554x; 1.0253x over previous
//
#include <hip/hip_runtime.h>
#include <hip/hip_bf16.h>
#include <stdint.h>

using bf16 = __hip_bfloat16;
typedef __attribute__((ext_vector_type(8))) short bf16x8;
typedef __attribute__((ext_vector_type(4))) float f32x4;
typedef __attribute__((ext_vector_type(2))) float f32x2;

#define NN 50000
#define NE 400000
#define NG 64
#define NHEADS 4
#define FIN 64
#define HID 96
#define CC3 64
#define NOUT 10

#define SCAN_BLOCK 256
#define NPART ((NN + SCAN_BLOCK - 1) / SCAN_BLOCK)   // 196 (<=256)

__device__ __forceinline__ float b2f(bf16 h){ return __bfloat162float(h); }
__device__ __forceinline__ bf16 f2b(float f){ return __float2bfloat16(f); }

// ---------------- prologue: cast x f32 -> bf16 ----------------
__global__ __launch_bounds__(256) void castx_kernel(const float* __restrict__ s,
                                                    bf16* __restrict__ d, int n){
  for (int i = blockIdx.x*256 + threadIdx.x; i < n; i += gridDim.x*256)
    d[i] = f2b(s[i]);
}

// ---------------- prologue: transpose weights f32[K,Nc] -> bf16 WT[Nc,K] ----------------
#define NTJOBS 5
struct TransJobs {
  const float* W[NTJOBS];
  bf16*        WT[NTJOBS];
  int          K[NTJOBS];
  int          Nc[NTJOBS];
};
__global__ __launch_bounds__(256) void trans_kernel(TransJobs j){
  for (int t=0; t<NTJOBS; ++t){
    int K = j.K[t], Nc = j.Nc[t], total = K*Nc;
    for (int i = blockIdx.x*256 + threadIdx.x; i < total; i += gridDim.x*256){
      int k = i / Nc, n = i % Nc;
      j.WT[t][(size_t)n*K + k] = f2b(j.W[t][i]);
    }
  }
}

// ---------------- CSR build ----------------
__global__ void deg_kernel(const int* __restrict__ ei, int* __restrict__ deg){
  int e = blockIdx.x*256 + threadIdx.x;
  if (e < NE) atomicAdd(&deg[ei[NE + e]], 1);
}

__global__ __launch_bounds__(256) void scan_part_kernel(const int* __restrict__ deg,
                                                        int* __restrict__ partials){
  int i = blockIdx.x*SCAN_BLOCK + threadIdx.x;
  int v = (i < NN) ? deg[i] : 0;
  __shared__ int ws[4];
  int lane = threadIdx.x & 63, w = threadIdx.x >> 6;
  int s = v;
  #pragma unroll
  for (int m=1;m<64;m<<=1) s += __shfl_xor(s,m);
  if (lane==0) ws[w]=s;
  __syncthreads();
  if (threadIdx.x==0) partials[blockIdx.x] = ws[0]+ws[1]+ws[2]+ws[3];
}

__global__ __launch_bounds__(256) void scan_top_kernel(int* __restrict__ partials,
                                                       int* __restrict__ off){
  __shared__ int buf[256];
  int t = threadIdx.x;
  int v = (t < NPART) ? partials[t] : 0;
  buf[t] = v; __syncthreads();
  for (int s=1;s<256;s<<=1){
    int x = (t>=s) ? buf[t-s] : 0;
    __syncthreads();
    buf[t] += x;
    __syncthreads();
  }
  if (t < NPART) partials[t] = buf[t] - v;   // exclusive
  if (t == 0) off[NN] = buf[255];
}

__global__ __launch_bounds__(256) void scan_final_kernel(const int* __restrict__ deg,
    const int* __restrict__ partials, int* __restrict__ off, int* __restrict__ cursor){
  __shared__ int buf[256];
  int i = blockIdx.x*SCAN_BLOCK + threadIdx.x;
  int t = threadIdx.x;
  int v = (i<NN) ? deg[i] : 0;
  buf[t] = v; __syncthreads();
  for (int s=1;s<256;s<<=1){
    int x = (t>=s) ? buf[t-s] : 0;
    __syncthreads();
    buf[t] += x;
    __syncthreads();
  }
  int ex = partials[blockIdx.x] + buf[t] - v;
  if (i<NN){ off[i]=ex; cursor[i]=ex; }
}

__global__ void scatter_kernel(const int* __restrict__ ei, int* __restrict__ cursor,
                               int* __restrict__ csr_src){
  int e = blockIdx.x*256 + threadIdx.x;
  if (e < NE){
    int d = ei[NE + e];
    int slot = atomicAdd(&cursor[d], 1);
    csr_src[slot] = ei[e];
  }
}

// ---------------- MFMA GEMM, fused main(fp8)+self(bf16) outputs ----------------
// WT[NcTotal,K] bf16 (concat: main cols then self cols). A-frags staged once.
// cols < ncMain  -> fp8 e4m3 byte store to outMain[row*ncMain+col], bias=biasMain
// cols >= ncMain -> bf16 store to outSelf[row*ncSelf+(col-ncMain)], bias=biasSelf
// grid = (ceil(M/128), ceil((NcTotal/16)/8)); block = 4 waves; wave tile 32 rows.
template<int K>
__global__ __launch_bounds__(256) void gemm_mfma(const bf16* __restrict__ A,
    const bf16* __restrict__ WT, const float* __restrict__ biasMain,
    const float* __restrict__ biasSelf, uint8_t* __restrict__ outMain,
    int ncMain, bf16* __restrict__ outSelf, int ncTotal, int Mrows)
{
  constexpr int KT = K/32;
  const int wave = threadIdx.x >> 6, lane = threadIdx.x & 63;
  const int r0 = blockIdx.x*128 + wave*32;
  const int lm = lane & 15, q = lane >> 4;
  const bf16x8 zfrag = {0,0,0,0,0,0,0,0};
  const int ncSelf = ncTotal - ncMain;

  bf16x8 afrag[2][KT];
  #pragma unroll
  for (int i=0;i<2;++i){
    int row = r0 + i*16 + lm;
    #pragma unroll
    for (int kt=0; kt<KT; ++kt)
      afrag[i][kt] = (row < Mrows) ? *(const bf16x8*)(A + (size_t)row*K + kt*32 + q*8) : zfrag;
  }

  const int t0 = blockIdx.y*8, t1 = min(t0+8, ncTotal/16);
  for (int ct=t0; ct<t1; ++ct){
    const int col = ct*16 + lm;
    f32x4 acc[2] = {};
    #pragma unroll
    for (int kt=0; kt<KT; ++kt){
      bf16x8 bfrag = *(const bf16x8*)(WT + (size_t)col*K + kt*32 + q*8);
      #pragma unroll
      for (int i=0;i<2;++i)
        acc[i] = __builtin_amdgcn_mfma_f32_16x16x32_bf16(afrag[i][kt], bfrag, acc[i], 0,0,0);
    }
    if (col < ncMain){
      float bv = biasMain[col];
      #pragma unroll
      for (int i=0;i<2;++i){
        #pragma unroll
        for (int r=0;r<4;++r){
          int row = r0 + i*16 + q*4 + r;
          if (row < Mrows){
            float v = acc[i][r] + bv;
            int pk = __builtin_amdgcn_cvt_pk_fp8_f32(v, v, 0, false);
            outMain[(size_t)row*ncMain + col] = (uint8_t)(pk & 0xff);
          }
        }
      }
    } else {
      float bv = biasSelf[col - ncMain];
      #pragma unroll
      for (int i=0;i<2;++i){
        #pragma unroll
        for (int r=0;r<4;++r){
          int row = r0 + i*16 + q*4 + r;
          if (row < Mrows) outSelf[(size_t)row*ncSelf + (col-ncMain)] = f2b(acc[i][r] + bv);
        }
      }
    }
  }
}

// ---------------- per-node attention exp-logits (fp8 messages, f32 att) ----------------
// EL[n,h] = exp(clamp(leaky_relu(sum_c M8[n,h*C+c]*att[h,c], 0.2), +-60))
__global__ void expl_kernel(const uint8_t* __restrict__ M8, const float* __restrict__ att,
                            float* __restrict__ EL, int C){
  int t = blockIdx.x*256 + threadIdx.x;
  if (t >= NN*NHEADS) return;
  int n = t >> 2, h = t & 3;
  const uint2* row = (const uint2*)(M8 + (size_t)n*NHEADS*C + h*C);
  const float* av  = att + h*C;
  float acc = 0.f;
  for (int c8=0; c8<C/8; ++c8){
    uint2 u = row[c8];
    f32x2 a0 = __builtin_amdgcn_cvt_pk_f32_fp8((int)u.x, false);
    f32x2 a1 = __builtin_amdgcn_cvt_pk_f32_fp8((int)u.x, true);
    f32x2 a2 = __builtin_amdgcn_cvt_pk_f32_fp8((int)u.y, false);
    f32x2 a3 = __builtin_amdgcn_cvt_pk_f32_fp8((int)u.y, true);
    const float* af = av + 8*c8;
    acc += a0.x*af[0] + a0.y*af[1] + a1.x*af[2] + a1.y*af[3]
         + a2.x*af[4] + a2.y*af[5] + a3.x*af[6] + a3.y*af[7];
  }
  float l = (acc >= 0.f) ? acc : 0.2f*acc;
  l = fminf(fmaxf(l, -60.f), 60.f);
  EL[t] = __expf(l);
}

// ---------------- conv aggregation: one wave per dst node, single pass, fp8 gather ----
template<int C>
__global__ __launch_bounds__(256) void conv_agg(const int* __restrict__ off,
    const int* __restrict__ csr_src, const float* __restrict__ EL,
    const uint8_t* __restrict__ M8, const bf16* __restrict__ Hself,
    bf16* __restrict__ Hout)
{
  constexpr int R = 4*C;          // row bytes (fp8) == channel count
  __shared__ float red[4][R];
  const int wave = threadIdx.x >> 6, lane = threadIdx.x & 63;
  const int n = blockIdx.x*4 + wave;
  const int e0 = off[n], e1 = off[n+1];

  const bool active = (8*lane) < R;
  const int hidx = (8*lane) / C;     // head of my 8-channel chunk (C%8==0)
  float acc[8] = {0,0,0,0,0,0,0,0};
  float dnl = 0.f;

  for (int base=e0; base<e1; base+=64){
    const int cnt = min(64, e1-base);
    int sreg = 0;
    float4 el = make_float4(0.f,0.f,0.f,0.f);
    if (lane < cnt){
      sreg = csr_src[base+lane];                       // coalesced
      el = *(const float4*)(EL + 4*(size_t)sreg);      // parallel gather
    }
    #pragma unroll 4
    for (int j=0; j<cnt; ++j){
      int s = __shfl(sreg, j);                         // v_readlane -> SGPR
      float ex=__shfl(el.x,j), ey=__shfl(el.y,j), ez=__shfl(el.z,j), ew=__shfl(el.w,j);
      float wl = (hidx==0)?ex:(hidx==1)?ey:(hidx==2)?ez:ew;
      dnl += wl;
      if (active){
        const uint2* qp = (const uint2*)(M8 + (size_t)s*R) + lane;
        uint2 u = *qp;
        f32x2 a0 = __builtin_amdgcn_cvt_pk_f32_fp8((int)u.x, false);
        f32x2 a1 = __builtin_amdgcn_cvt_pk_f32_fp8((int)u.x, true);
        f32x2 a2 = __builtin_amdgcn_cvt_pk_f32_fp8((int)u.y, false);
        f32x2 a3 = __builtin_amdgcn_cvt_pk_f32_fp8((int)u.y, true);
        acc[0] += a0.x*wl;  acc[1] += a0.y*wl;
        acc[2] += a1.x*wl;  acc[3] += a1.y*wl;
        acc[4] += a2.x*wl;  acc[5] += a2.y*wl;
        acc[6] += a3.x*wl;  acc[7] += a3.y*wl;
      }
    }
  }

  float rd = 1.f/(dnl + 1e-16f);
  if (active){
    #pragma unroll
    for (int j=0;j<8;++j) red[wave][8*lane+j] = acc[j]*rd;
  }
  __syncthreads();

  // epilogue: mean over heads + self (in-place safe: one thread per element)
  for (int c=lane; c<C; c+=64){
    float v = 0.25f*(red[wave][c] + red[wave][C+c] + red[wave][2*C+c] + red[wave][3*C+c]);
    float sv = b2f(Hself[(size_t)n*C + c]);
    Hout[(size_t)n*C + c] = f2b(v + sv);
  }
}

// ---------------- global mean pool, stage 1: parallel segmented sum ----------------
__global__ __launch_bounds__(256) void pool_kernel(const bf16* __restrict__ H3,
    const int* __restrict__ batch, float* __restrict__ psum){
  const int wave = threadIdx.x >> 6, lane = threadIdx.x & 63;
  const int row0 = (blockIdx.x*4 + wave)*64;
  if (row0 >= NN) return;
  const int cnt = min(64, NN - row0);
  int bv = (lane < cnt) ? batch[row0 + lane] : -1;
  int cur = __shfl(bv, 0);
  float acc = 0.f;
  for (int j=0; j<cnt; ++j){
    int g = __shfl(bv, j);
    if (g != cur){ atomicAdd(&psum[cur*CC3 + lane], acc); acc = 0.f; cur = g; }
    acc += b2f(H3[(size_t)(row0 + j)*CC3 + lane]);
  }
  atomicAdd(&psum[cur*CC3 + lane], acc);
}

// ---------------- classifier + log_softmax (f32 weights & output) ----------------
__global__ __launch_bounds__(64) void fc_kernel(const float* __restrict__ psum,
    const int* __restrict__ batch, const float* __restrict__ Wfc,
    const float* __restrict__ bfc, float* __restrict__ out){
  int g = blockIdx.x, t = threadIdx.x;
  __shared__ int sb[2];
  if (t < 2){
    int target = g + t;
    int lo=0, hi=NN;
    while (lo<hi){ int mid=(lo+hi)>>1; if (batch[mid]<target) lo=mid+1; else hi=mid; }
    sb[t]=lo;
  }
  __syncthreads();
  float cnt = (float)(sb[1]-sb[0]);
  __shared__ float p[CC3];
  __shared__ float lg[NOUT];
  p[t] = psum[g*CC3 + t] / fmaxf(cnt, 1.0f);
  __syncthreads();
  if (t < NOUT){
    float a = bfc[t];
    for (int c=0;c<CC3;++c) a += p[c]*Wfc[c*NOUT + t];
    lg[t] = a;
  }
  __syncthreads();
  if (t < NOUT){
    float m = -INFINITY;
    #pragma unroll
    for (int i=0;i<NOUT;++i) m = fmaxf(m, lg[i]);
    float s = 0.f;
    #pragma unroll
    for (int i=0;i<NOUT;++i) s += __expf(lg[i]-m);
    out[g*NOUT + t] = lg[t] - m - __logf(s);
  }
}

extern "C" void kernel_launch(void* const* d_in, const int* in_sizes, int n_in,
                              void* d_out, int out_size, void* d_ws, size_t ws_size,
                              hipStream_t stream) {
  const float* xf    = (const float*)d_in[0];
  const int*   ei    = (const int*)d_in[1];
  const int*   batch = (const int*)d_in[2];
  const float* pWm1  = (const float*)d_in[3];
  const float* pbm1  = (const float*)d_in[4];
  const float* patt1 = (const float*)d_in[5];
  const float* pWs1  = (const float*)d_in[6];
  const float* pbs1  = (const float*)d_in[7];
  const float* pWm2  = (const float*)d_in[8];
  const float* pbm2  = (const float*)d_in[9];
  const float* patt2 = (const float*)d_in[10];
  const float* pWm3  = (const float*)d_in[11];
  const float* pbm3  = (const float*)d_in[12];
  const float* patt3 = (const float*)d_in[13];
  const float* pWs3  = (const float*)d_in[14];
  const float* pbs3  = (const float*)d_in[15];
  const float* pWfc  = (const float*)d_in[16];
  const float* pbfc  = (const float*)d_in[17];

  // ---- workspace layout, lifetime-aliased ----
  char* p = (char*)d_ws;
  auto alloc = [&](size_t bytes)->char*{ char* q = p; p += (bytes + 255) & ~(size_t)255; return q; };
  int*     deg     = (int*)  alloc(NN*sizeof(int));
  int*     off     = (int*)  alloc((NN+1)*sizeof(int));
  int*     cursor  = (int*)  alloc(NN*sizeof(int));
  int*     csr_src = (int*)  alloc(NE*sizeof(int));
  int*     partials= (int*)  alloc(NPART*sizeof(int));
  float*   EL      = (float*)alloc((size_t)NN*4*sizeof(float));
  uint8_t* Mb8     = (uint8_t*)alloc((size_t)NN*384);            // 19.2 MB fp8, reused per layer
  bf16*    H1b     = (bf16*) alloc((size_t)NN*96*sizeof(bf16));  // 9.6 MB; H3 aliases this
  bf16*    H2b     = (bf16*) alloc((size_t)NN*96*sizeof(bf16));  // 9.6 MB
  float*   psum    = (float*)alloc((size_t)NG*CC3*sizeof(float));
  bf16*    xb      = (bf16*) alloc((size_t)NN*FIN*sizeof(bf16)); // 6.4 MB
  // concatenated transposed bf16 weights [NcTotal,K] (main cols then self cols)
  bf16*  WT1cat = (bf16*)alloc((size_t)480*FIN*sizeof(bf16));   // Wm1 (384) | Ws1 (96)
  bf16*  Wm2T   = (bf16*)alloc((size_t)384*HID*sizeof(bf16));
  bf16*  WT3cat = (bf16*)alloc((size_t)320*HID*sizeof(bf16));   // Wm3 (256) | Ws3 (64)
  bf16*  H3b = H1b;   // H1 dead after layer-2 aggregation (stream-ordered)

  // ---- prologue: x cast + weight transposes (into concat layout) ----
  castx_kernel<<<1024, 256, 0, stream>>>(xf, xb, NN*FIN);
  TransJobs tj;
  tj.W[0]=pWm1; tj.WT[0]=WT1cat;          tj.K[0]=FIN; tj.Nc[0]=384;
  tj.W[1]=pWs1; tj.WT[1]=WT1cat+384*FIN;  tj.K[1]=FIN; tj.Nc[1]=96;
  tj.W[2]=pWm2; tj.WT[2]=Wm2T;            tj.K[2]=HID; tj.Nc[2]=384;
  tj.W[3]=pWm3; tj.WT[3]=WT3cat;          tj.K[3]=HID; tj.Nc[3]=256;
  tj.W[4]=pWs3; tj.WT[4]=WT3cat+256*HID;  tj.K[4]=HID; tj.Nc[4]=64;
  trans_kernel<<<256, 256, 0, stream>>>(tj);

  // ---- CSR build (hierarchical scan; reused by all 3 layers) ----
  hipMemsetAsync(deg, 0, NN*sizeof(int), stream);
  hipMemsetAsync(psum, 0, NG*CC3*sizeof(float), stream);
  deg_kernel<<<(NE+255)/256, 256, 0, stream>>>(ei, deg);
  scan_part_kernel<<<NPART, 256, 0, stream>>>(deg, partials);
  scan_top_kernel<<<1, 256, 0, stream>>>(partials, off);
  scan_final_kernel<<<NPART, 256, 0, stream>>>(deg, partials, off, cursor);
  scatter_kernel<<<(NE+255)/256, 256, 0, stream>>>(ei, cursor, csr_src);

  const int MB128 = (NN + 127)/128;       // 391 row blocks (MFMA)
  const int LB = (NN*4 + 255)/256;        // expl blocks
  const int AB = NN/4;                    // 12500 agg blocks (4 waves each)
  const int PB = (NN + 255)/256;          // pool blocks

  // ---- layer 1: FIN=64 -> HID=96 (fused main+self; 480 cols -> 30 tiles -> y=4) ----
  gemm_mfma<64><<<dim3(MB128,4), 256, 0, stream>>>(xb, WT1cat, pbm1, pbs1,
                                                   Mb8, 384, H1b, 480, NN);
  expl_kernel<<<LB, 256, 0, stream>>>(Mb8, patt1, EL, 96);
  conv_agg<96><<<AB, 256, 0, stream>>>(off, csr_src, EL, Mb8, H1b, H1b);   // in-place += agg

  // ---- layer 2: HID -> HID (identity self; 384 cols -> y=3) ----
  gemm_mfma<96><<<dim3(MB128,3), 256, 0, stream>>>(H1b, Wm2T, pbm2, pbm2,
                                                   Mb8, 384, nullptr, 384, NN);
  expl_kernel<<<LB, 256, 0, stream>>>(Mb8, patt2, EL, 96);
  conv_agg<96><<<AB, 256, 0, stream>>>(off, csr_src, EL, Mb8, H1b, H2b);

  // ---- layer 3: HID -> CC3=64 (fused main+self; 320 cols -> 20 tiles -> y=3) ----
  gemm_mfma<96><<<dim3(MB128,3), 256, 0, stream>>>(H2b, WT3cat, pbm3, pbs3,
                                                   Mb8, 256, H3b, 320, NN);
  expl_kernel<<<LB, 256, 0, stream>>>(Mb8, patt3, EL, 64);
  conv_agg<64><<<AB, 256, 0, stream>>>(off, csr_src, EL, Mb8, H3b, H3b);   // in-place += agg

  // ---- pool (2-stage) + classifier ----
  pool_kernel<<<PB, 256, 0, stream>>>(H3b, batch, psum);
  fc_kernel<<<NG, 64, 0, stream>>>(psum, batch, pWfc, pbfc, (float*)d_out);
}